// Round 6
// baseline (497.857 us; speedup 1.0000x reference)
//
#include <hip/hip_runtime.h>
#include <hip/hip_bf16.h>
#include <stdint.h>

typedef __bf16 bf16;
typedef __bf16 bf16x8 __attribute__((ext_vector_type(8)));
typedef __bf16 bf16x4 __attribute__((ext_vector_type(4)));
typedef float f32x4 __attribute__((ext_vector_type(4)));

#define AS1 __attribute__((address_space(1)))
#define AS3 __attribute__((address_space(3)))

// B=4, S=256, H=12, DH=64(pad 128), D=768, FD=2048, FU=2048
// R25 (this round): R24 proved the final GEMM is NOT HBM-bound (FETCH 253->76MB,
// dur unchanged). Per-K-step arithmetic: MFMA 2483 cyc/CU vs LDS-read 2304
// cyc/CU; measured dur = SUM not MAX -> barrier-lockstep serializes the two
// pipes (all waves read, then all waves MFMA). Fix = 4-phase split of the
// K-step (h2 x mi-half): each phase {4-8 ds_read -> 16 MFMA in setprio(1)}
// fenced by s_barrier, so waves de-phase and LDS/MFMA pipes cross-fill
// (T3 phase-split + T5 setprio; geometry already matches the m201 template).

__device__ __forceinline__ void gld16(const bf16* g, bf16* l) {
  __builtin_amdgcn_global_load_lds((AS1 void*)g, (AS3 void*)l, 16, 0, 0);
}

__global__ void k_sentinel(float* __restrict__ out) {
  int i = blockIdx.x * 256 + threadIdx.x;
  if (i < 2097152) out[i] = 1048576.0f;
}

// ---------------- prep kernels ----------------

__global__ void k_invln(const float* __restrict__ ln, float* __restrict__ invln) {
  int i = blockIdx.x * 256 + threadIdx.x;
  if (i < 1024) invln[i] = 1.0f / ln[i];
}

// vectorized fp32 -> bf16 cast, n4 = n/4
__global__ void k_cast4(const float* __restrict__ s, bf16* __restrict__ d, int n4) {
  int i = blockIdx.x * 256 + threadIdx.x;
  if (i < n4) {
    float4 v = *(const float4*)(s + (long)i * 4);
    bf16x4 o;
    o[0] = (bf16)v.x; o[1] = (bf16)v.y; o[2] = (bf16)v.z; o[3] = (bf16)v.w;
    *(bf16x4*)(d + (long)i * 4) = o;
  }
}

// int32 0/1 mask -> bf16, n4 = n/4
__global__ void k_maskb(const int* __restrict__ m, bf16* __restrict__ d, int n4) {
  int i = blockIdx.x * 256 + threadIdx.x;
  if (i < n4) {
    int4 v = *(const int4*)(m + (long)i * 4);
    bf16x4 o;
    o[0] = (bf16)(float)v.x; o[1] = (bf16)(float)v.y;
    o[2] = (bf16)(float)v.z; o[3] = (bf16)(float)v.w;
    *(bf16x4*)(d + (long)i * 4) = o;
  }
}

// probsT[b][q][h*256+s] = bf16(probs[b,h,q,s])   (contiguous in s both sides)
__global__ void k_probsT(const float* __restrict__ probs, bf16* __restrict__ pT) {
  int i = blockIdx.x * 256 + threadIdx.x;   // 786432 vec4s
  if (i < 786432) {
    long idx = (long)i * 4;
    int s  = (int)(idx & 255);
    int q  = (int)((idx >> 8) & 255);
    int hb = (int)(idx >> 16);
    int h = hb % 12, b = hb / 12;
    float4 v = *(const float4*)(probs + idx);
    bf16x4 o;
    o[0] = (bf16)v.x; o[1] = (bf16)v.y; o[2] = (bf16)v.z; o[3] = (bf16)v.w;
    *(bf16x4*)(pT + (long)b * 786432 + (long)q * 3072 + h * 256 + s) = o;
  }
}

__global__ void k_WO(const float* __restrict__ W_O, bf16* __restrict__ WOb) {
  int i = blockIdx.x * 256 + threadIdx.x;           // 12*128*768
  int o = i % 768, r = (i / 768) & 127, h = i / (768 * 128);
  WOb[i] = (r < 64) ? (bf16)W_O[(long)(h * 64 + r) * 768 + o] : (bf16)0.0f;
}

// WVt[h][k<128][i<768] = W_V[h,i,k]  (tiled transpose, zero-pad k>=64)
__global__ void k_WVtT(const float* __restrict__ wv, bf16* __restrict__ WVt) {
  __shared__ float tile[32][33];
  int h = blockIdx.z;                 // 12
  int k0 = blockIdx.x * 32;           // 0..96
  int i0 = blockIdx.y * 32;           // 24 tiles
  int lane = threadIdx.x & 31, rg = threadIdx.x >> 5;
  if (k0 < 64) {
    for (int r = rg; r < 32; r += 8)
      tile[r][lane] = wv[((long)(h * 768 + i0 + r)) * 64 + k0 + lane];
    __syncthreads();
    for (int r = rg; r < 32; r += 8)
      WVt[((long)h * 128 + k0 + r) * 768 + i0 + lane] = (bf16)tile[lane][r];
  } else {
    for (int r = rg; r < 32; r += 8)
      WVt[((long)h * 128 + k0 + r) * 768 + i0 + lane] = (bf16)0.0f;
  }
}

// W_Ot[h][o][k64] = W_O[h,k,o]  (tiled transpose)
__global__ void k_WOt(const float* __restrict__ wo, bf16* __restrict__ W_Ot) {
  __shared__ float tile[32][33];
  int h = blockIdx.z;                 // 12
  int k0 = blockIdx.x * 32;           // 0..32
  int o0 = blockIdx.y * 32;           // 24 tiles
  int lane = threadIdx.x & 31, rg = threadIdx.x >> 5;
  for (int r = rg; r < 32; r += 8)
    tile[r][lane] = wo[((long)(h * 64 + k0 + r)) * 768 + o0 + lane];
  __syncthreads();
  for (int r = rg; r < 32; r += 8)
    W_Ot[((long)(h * 768 + o0 + r)) * 64 + k0 + lane] = (bf16)tile[lane][r];
}

// updWt[u][i] = up_dec_W[i][u]  (tiled transpose)
__global__ void k_updWtT(const float* __restrict__ u, bf16* __restrict__ d) {
  __shared__ float tile[32][33];
  int u0 = blockIdx.x * 32;           // 64 tiles
  int i0 = blockIdx.y * 32;           // 24 tiles
  int lane = threadIdx.x & 31, rg = threadIdx.x >> 5;
  for (int r = rg; r < 32; r += 8)
    tile[r][lane] = u[((long)(i0 + r)) * 2048 + u0 + lane];
  __syncthreads();
  for (int r = rg; r < 32; r += 8)
    d[((long)(u0 + r)) * 768 + i0 + lane] = (bf16)tile[lane][r];
}

// Xb[b*256+s][d] = resid[b,s,d] * invln (row-major bf16, no transpose)
__global__ void k_Xb(const float* __restrict__ resid, const float* __restrict__ invln,
                     bf16* __restrict__ Xb) {
  int i = blockIdx.x * 256 + threadIdx.x;   // 196608 vec4s
  if (i < 196608) {
    long idx = (long)i * 4;
    float il = invln[idx / 768];            // 4|768 so chunk never straddles rows
    float4 v = *(const float4*)(resid + idx);
    bf16x4 o;
    o[0] = (bf16)(v.x * il); o[1] = (bf16)(v.y * il);
    o[2] = (bf16)(v.z * il); o[3] = (bf16)(v.w * il);
    *(bf16x4*)(Xb + idx) = o;
  }
}

// Ut[b][u][s] = pruned[b,s,u] * invln  (tiled transpose)
__global__ void k_UtT(const float* __restrict__ pr, const float* __restrict__ invln,
                      bf16* __restrict__ Ut) {
  __shared__ float tile[32][33];
  int b = blockIdx.z, u0 = blockIdx.x * 32, s0 = blockIdx.y * 32;  // (64, 8, 4)
  int lane = threadIdx.x & 31, rg = threadIdx.x >> 5;
  for (int r = rg; r < 32; r += 8) {
    int s = s0 + r;
    tile[r][lane] = pr[((long)(b * 256 + s)) * 2048 + u0 + lane] * invln[b * 256 + s];
  }
  __syncthreads();
  for (int r = rg; r < 32; r += 8)
    Ut[((long)b * 2048 + u0 + r) * 256 + s0 + lane] = (bf16)tile[lane][r];
}

// append enc_W (bf16) as the 768-column K-tail of B_g
__global__ void k_append(const bf16* __restrict__ encWb, bf16* __restrict__ Bt, long ldb) {
  int i = blockIdx.x * 256 + threadIdx.x;   // 196608 vec8s
  if (i < 196608) {
    long idx = (long)i * 8;
    int f = (int)(idx / 768), d = (int)(idx % 768);
    *(bf16x8*)(Bt + (long)f * ldb + d) = *(const bf16x8*)(encWb + idx);
  }
}

// ---------------- bias chain (fp32, block-parallel) ----------------

__device__ __forceinline__ float blk_reduce(float s) {
  __shared__ float red[256];
  red[threadIdx.x] = s; __syncthreads();
  for (int o = 128; o > 0; o >>= 1) {
    if ((int)threadIdx.x < o) red[threadIdx.x] += red[threadIdx.x + o];
    __syncthreads();
  }
  float r = red[0]; __syncthreads();
  return r;
}

__global__ void k_bias_t(const float* __restrict__ W_V, const float* __restrict__ up_b,
                         float* __restrict__ t_hk) {
  int j = blockIdx.x, h = j >> 6, k = j & 63;
  float s = 0.f;
  for (int m = threadIdx.x; m < 768; m += 256)
    s += W_V[((long)(h * 768 + m)) * 64 + k] * up_b[m];
  float r = blk_reduce(s);
  if (threadIdx.x == 0) t_hk[j] = r;
}

__global__ void k_bias_w(const float* __restrict__ W_O, const float* __restrict__ t_hk,
                         float* __restrict__ w) {
  int d = blockIdx.x;
  float s = 0.f;
  for (int j = threadIdx.x; j < 768; j += 256)
    s += W_O[(long)j * 768 + d] * t_hk[j];
  float r = blk_reduce(s);
  if (threadIdx.x == 0) w[d] = r;
}

__global__ void k_bias_c(const float* __restrict__ enc_W, const float* __restrict__ enc_b,
                         const float* __restrict__ b_dec, const float* __restrict__ w,
                         float* __restrict__ c0, float* __restrict__ c1) {
  int f = blockIdx.x;
  float s0 = 0.f, s1 = 0.f;
  for (int d = threadIdx.x; d < 768; d += 256) {
    float e = enc_W[(long)f * 768 + d];
    s0 += e * b_dec[d];
    s1 += e * w[d];
  }
  float r0 = blk_reduce(s0);
  float r1 = blk_reduce(s1);
  if (threadIdx.x == 0) { c0[f] = enc_b[f] - r0; c1[f] = r1; }
}

// ---------------- GEMM (BT form: C[m,n] = sum_k A[m,k]*B[n,k]) ----------------
// BK=64, XOR-swizzled staging. K (and kChunk) must be multiples of 64.
// mode 0: bf16 store; mode 1: *= bf16 mask, bf16 store;
// mode 2: split-K fp32 overwrite; mode 3: split-K fp32 read-accumulate
__global__ __launch_bounds__(256)
void gemm_bt(const bf16* __restrict__ A, const bf16* __restrict__ B, void* __restrict__ Cv,
             int M, int N, int K,
             long lda, long ldb, long ldc,
             int batchH,
             long sa_b, long sa_h, long sb_b, long sb_h, long sc_b, long sc_h,
             int mode, int kChunk,
             const bf16* __restrict__ mask, long mask_ld)
{
  __shared__ __align__(16) bf16 Asm[128 * 64];
  __shared__ __align__(16) bf16 Bsm[128 * 64];

  const int t = threadIdx.x;

  // bijective XCD-aware remap of the (x,y) tile id (m204 formula)
  const int nbx = gridDim.x, nby = gridDim.y;
  const int nxy = nbx * nby;
  int orig = blockIdx.x + nbx * blockIdx.y;
  int qq = nxy >> 3, rr = nxy & 7;
  int xcd = orig & 7, lid = orig >> 3;
  int swz = (xcd < rr) ? (xcd * (qq + 1) + lid)
                       : (rr * (qq + 1) + (xcd - rr) * qq + lid);
  const int m0 = (swz % nby) * 128;
  const int n0 = (swz / nby) * 128;

  long aoff, boff, coff;
  int k0, k1;
  if (mode >= 2) {
    int z = blockIdx.z;
    aoff = 0; boff = 0;
    coff = (long)z * (long)M * ldc;
    k0 = z * kChunk; k1 = k0 + kChunk; if (k1 > K) k1 = K;
  } else {
    int z = blockIdx.z;
    int bb = z / batchH, hh = z - bb * batchH;
    aoff = (long)bb * sa_b + (long)hh * sa_h;
    boff = (long)bb * sb_b + (long)hh * sb_h;
    coff = (long)bb * sc_b + (long)hh * sc_h;
    k0 = 0; k1 = K;
  }

  const bf16* Ab = A + aoff + (long)m0 * lda;
  const bf16* Bb = B + boff + (long)n0 * ldb;

  const int r0 = t >> 3;           // 0..31 (staging row within 32-row group)
  const int g8 = t & 7;            // staging col-group (LDS slot)

  const int L = t & 63, w = t >> 6;
  const int wm = (w & 1) * 64, wn = (w >> 1) * 64;
  const int r16 = L & 15, q = L >> 4;

  f32x4 acc[4][4];
#pragma unroll
  for (int i = 0; i < 4; i++)
#pragma unroll
    for (int j = 0; j < 4; j++) acc[i][j] = (f32x4){0.f, 0.f, 0.f, 0.f};

  for (int kt = k0; kt < k1; kt += 64) {
#pragma unroll
    for (int j = 0; j < 4; j++) {
      int row = j * 32 + r0;
      int sc = ((g8 ^ (row & 7)) << 3);      // source col swizzle
      gld16(Ab + (long)row * lda + (kt + sc), &Asm[j * 2048 + t * 8]);
      gld16(Bb + (long)row * ldb + (kt + sc), &Bsm[j * 2048 + t * 8]);
    }
    __syncthreads();

#pragma unroll
    for (int h2 = 0; h2 < 2; h2++) {
      bf16x8 af[4], bfr[4];
#pragma unroll
      for (int i = 0; i < 4; i++) {
        int ra = wm + i * 16 + r16;
        af[i]  = *(const bf16x8*)&Asm[ra * 64 + ((((h2 << 2) + q) ^ (ra & 7)) << 3)];
        int rb = wn + i * 16 + r16;
        bfr[i] = *(const bf16x8*)&Bsm[rb * 64 + ((((h2 << 2) + q) ^ (rb & 7)) << 3)];
      }
#pragma unroll
      for (int mi = 0; mi < 4; mi++)
#pragma unroll
        for (int ni = 0; ni < 4; ni++)
          acc[mi][ni] = __builtin_amdgcn_mfma_f32_16x16x32_bf16(af[mi], bfr[ni], acc[mi][ni], 0, 0, 0);
    }
    __syncthreads();
  }

  if (mode >= 2) {
    float* C = (float*)Cv;
#pragma unroll
    for (int mi = 0; mi < 4; mi++)
#pragma unroll
      for (int ni = 0; ni < 4; ni++)
#pragma unroll
        for (int r = 0; r < 4; r++) {
          int gm = m0 + wm + mi * 16 + q * 4 + r;
          int gn = n0 + wn + ni * 16 + r16;
          long idx = coff + (long)gm * ldc + gn;
          float v = acc[mi][ni][r];
          if (mode == 3) v += C[idx];
          C[idx] = v;
        }
  } else {
    bf16* C = (bf16*)Cv;
#pragma unroll
    for (int mi = 0; mi < 4; mi++)
#pragma unroll
      for (int ni = 0; ni < 4; ni++)
#pragma unroll
        for (int r = 0; r < 4; r++) {
          int gm = m0 + wm + mi * 16 + q * 4 + r;
          int gn = n0 + wn + ni * 16 + r16;
          float v = acc[mi][ni][r];
          if (mode == 1) v *= (float)mask[(long)gm * mask_ld + gn];
          C[coff + (long)gm * ldc + gn] = (bf16)v;
        }
  }
}

// ------------- 256x256-tile split-K GEMM (final GEMM only) -------------------
// C[m,n] (+)= sum_k A[m,k]*B[n,k], fp32 C. 512 threads = 8 waves (2M x 4N),
// per-wave 128x64 output. BK=64. 2 LDS buffers (128 KiB), depth-1 prefetch,
// counted vmcnt(8) (0 only at epilogue).
// K-step is split into 4 phases (h2 x mi-half): each phase {4-8 ds_read ->
// setprio(1) 16 MFMA setprio(0)} fenced by s_barrier so the 8 waves de-phase
// and the LDS-read and MFMA pipes cross-fill instead of alternating in
// lockstep (R24: dur == LDS_time + MFMA_time, i.e. serialized).
// Work remap: z_slab = flat_id % nz (flat_id%8 = XCD) -> each XCD owns one
// K-slab; hot window ~384KB << 4MiB L2 (R24: FETCH 253->76MB).
// K, kChunk multiples of 64. mode 2 = overwrite, 3 = read-accumulate.
__global__ __launch_bounds__(512, 2)
void gemm_fp2(const bf16* __restrict__ A, const bf16* __restrict__ B,
              float* __restrict__ C,
              int M, int N, int K, long lda, long ldb, long ldc,
              int mode, int kChunk)
{
  __shared__ __align__(16) bf16 SM[2][2][16384];   // [buf][A|B][256*64]

  const int t = threadIdx.x;

  const int nz = gridDim.z;
  int fid = blockIdx.x + gridDim.x * (blockIdx.y + gridDim.y * blockIdx.z);
  const int z  = fid % nz;                 // K-slab, constant per XCD when nz=8
  const int t2 = fid / nz;                 // 0..31 (m,n)-tile within the slab
  const int m0 = (t2 >> 3) * 256;          // 4 m-tiles
  const int n0 = (t2 & 7) * 256;           // 8 n-tiles

  const long coff = (long)z * (long)M * ldc;
  int k0 = z * kChunk, k1 = k0 + kChunk; if (k1 > K) k1 = K;
  const int NT = (k1 > k0) ? (k1 - k0) >> 6 : 0;

  const bf16* Ab = A + (long)m0 * lda + k0;
  const bf16* Bb = B + (long)n0 * ldb + k0;

  const int sr = t >> 3;           // 0..63 staging row within 64-row group
  const int g8 = t & 7;            // staging col-group (LDS slot)

  const int L = t & 63, w = t >> 6;          // 8 waves
  const int wm = (w & 1) * 128;              // 2 waves over M (256)
  const int wn = (w >> 1) * 64;              // 4 waves over N (256)
  const int r16 = L & 15, q = L >> 4;

  f32x4 acc[8][4];
#pragma unroll
  for (int i = 0; i < 8; i++)
#pragma unroll
    for (int j = 0; j < 4; j++) acc[i][j] = (f32x4){0.f, 0.f, 0.f, 0.f};

  // stage K-tile tt into buffer buf: 8 gld16 per thread (4 A rounds, 4 B)
  auto stage = [&](int tt, int buf) {
    const bf16* Ap = Ab + (long)tt * 64;
    const bf16* Bp = Bb + (long)tt * 64;
#pragma unroll
    for (int j = 0; j < 4; j++) {
      int row = j * 64 + sr;
      int sc = ((g8 ^ (row & 7)) << 3);
      gld16(Ap + (long)row * lda + sc, &SM[buf][0][j * 4096 + t * 8]);
    }
#pragma unroll
    for (int j = 0; j < 4; j++) {
      int row = j * 64 + sr;
      int sc = ((g8 ^ (row & 7)) << 3);
      gld16(Bp + (long)row * ldb + sc, &SM[buf][1][j * 4096 + t * 8]);
    }
  };

  if (NT >= 1) stage(0, 0);

  for (int tt = 0; tt < NT; tt++) {
    const int buf = tt & 1;
    // Stage next tile into buf^1. Safe: the last phase barrier of tile tt-1
    // guarantees all waves finished reading buf^1 (tt=0: nothing read yet).
    if (tt + 1 < NT) {
      stage(tt + 1, buf ^ 1);
      asm volatile("s_waitcnt vmcnt(8)" ::: "memory");   // stage(tt) landed
    } else {
      asm volatile("s_waitcnt vmcnt(0)" ::: "memory");   // epilogue drain
    }
    __builtin_amdgcn_s_barrier();            // buf visible to all waves

    const bf16* As = &SM[buf][0][0];
    const bf16* Bs = &SM[buf][1][0];
#pragma unroll
    for (int h2 = 0; h2 < 2; h2++) {
      bf16x8 bfr[4];
#pragma unroll
      for (int i = 0; i < 4; i++) {
        int rb = wn + i * 16 + r16;
        bfr[i] = *(const bf16x8*)&Bs[rb * 64 + ((((h2 << 2) + q) ^ (rb & 7)) << 3)];
      }
#pragma unroll
      for (int ph = 0; ph < 2; ph++) {
        bf16x8 af[4];
#pragma unroll
        for (int i = 0; i < 4; i++) {
          int ra = wm + (ph * 4 + i) * 16 + r16;
          af[i] = *(const bf16x8*)&As[ra * 64 + ((((h2 << 2) + q) ^ (ra & 7)) << 3)];
        }
        __builtin_amdgcn_s_setprio(1);
#pragma unroll
        for (int mi = 0; mi < 4; mi++)
#pragma unroll
          for (int ni = 0; ni < 4; ni++)
            acc[ph * 4 + mi][ni] = __builtin_amdgcn_mfma_f32_16x16x32_bf16(
                af[mi], bfr[ni], acc[ph * 4 + mi][ni], 0, 0, 0);
        __builtin_amdgcn_s_setprio(0);
        __builtin_amdgcn_s_barrier();        // phase fence; last one doubles
      }                                      // as the stage-safety barrier
    }
  }

#pragma unroll
  for (int mi = 0; mi < 8; mi++)
#pragma unroll
    for (int ni = 0; ni < 4; ni++)
#pragma unroll
      for (int r = 0; r < 4; r++) {
        int gm = m0 + wm + mi * 16 + q * 4 + r;
        int gn = n0 + wn + ni * 16 + r16;
        long idx = coff + (long)gm * ldc + gn;
        float v = acc[mi][ni][r];
        if (mode == 3) v += C[idx];
        C[idx] = v;
      }
}

// ---------------- final reduce + bias epilogue (fp32 out, float4) ------------
__global__ void k_out(const float* __restrict__ Cp, const float* __restrict__ c0,
                      const float* __restrict__ c1, const float* __restrict__ invln,
                      float* __restrict__ out, int nsplit) {
  int i4 = blockIdx.x * 256 + threadIdx.x;          // 524288
  long i = (long)i4 * 4;
  int n = (int)(i & 2047), m = (int)(i >> 11);
  float4 v = *(const float4*)(Cp + i);
  for (int z = 1; z < nsplit; z++) {
    float4 u = *(const float4*)(Cp + i + (long)z * 2097152);
    v.x += u.x; v.y += u.y; v.z += u.z; v.w += u.w;
  }
  float il = invln[m];
  float4 a = *(const float4*)(c0 + n);
  float4 b = *(const float4*)(c1 + n);
  v.x += a.x + b.x * il;
  v.y += a.y + b.y * il;
  v.z += a.z + b.z * il;
  v.w += a.w + b.w * il;
  *(float4*)(out + i) = v;
}

// ---------------- host ----------------

extern "C" void kernel_launch(void* const* d_in, const int* in_sizes, int n_in,
                              void* d_out, int out_size, void* d_ws, size_t ws_size,
                              hipStream_t stream) {
  (void)out_size;
  float* out = (float*)d_out;

  // ---- resolve inputs by size (order-agnostic) ----
  int iresid = -1, iln = -1, iprobs = -1, iencb = -1, ipruned = -1, imask = -1;
  int iwo = -1, iwv = -1, iencw = -1, iupdw = -1, ibdec = -1, iupb = -1;
  for (int i = 0; i < n_in; i++) {
    switch (in_sizes[i]) {
      case 786432:  iresid  = i; break;
      case 1024:    iln     = i; break;
      case 3145728: iprobs  = i; break;
      case 2048:    iencb   = i; break;
      case 2097152: ipruned = i; break;
      case 4194304: imask   = i; break;
      case 589824:  if (iwo   < 0) iwo   = i; else iwv   = i; break;
      case 1572864: if (iencw < 0) iencw = i; else iupdw = i; break;
      case 768:     if (ibdec < 0) ibdec = i; else iupb  = i; break;
      default: break;
    }
  }
  bool ok = n_in == 12 && iresid >= 0 && iln >= 0 && iprobs >= 0 && iencb >= 0 &&
            ipruned >= 0 && imask >= 0 && iwo >= 0 && iwv >= 0 && iencw >= 0 &&
            iupdw >= 0 && ibdec >= 0 && iupb >= 0;
  if (!ok) { k_sentinel<<<8192, 256, 0, stream>>>(out); return; }

  const float* resid = (const float*)d_in[iresid];
  const float* lns   = (const float*)d_in[iln];
  const float* probs = (const float*)d_in[iprobs];
  const float* W_O   = (const float*)d_in[iwo];
  const float* W_V   = (const float*)d_in[iwv];
  const float* enc_W = (const float*)d_in[iencw];
  const float* enc_b = (const float*)d_in[iencb];
  const float* b_dec = (const float*)d_in[ibdec];
  const float* updW  = (const float*)d_in[iupdw];
  const float* up_b  = (const float*)d_in[iupb];
  const float* pruned= (const float*)d_in[ipruned];
  const int*   cmask = (const int*)d_in[imask];

  // ---- workspace sizing ----
  auto pad = [](size_t b) -> size_t { return (b + 255) & ~(size_t)255; };
  // overlay prep buffers (ALL dead before the first final-GEMM dispatch):
  const size_t prepB = pad(2359296) + pad(2359296) + pad(3145728) + pad(1572864) +
                       pad(3145728) + pad(1179648) + pad(3145728) + pad(18874368);
  // persistent (live across the g-loop): G_t, Ut, E1, probsT, maskb + smalls
  const size_t persB = pad(6291456) + pad(4194304) + pad(6291456) + pad(6291456) +
                       pad(8388608) + pad(4096) + pad(3072) + pad(3072) +
                       pad(8192) + pad(8192);
  auto needB = [&](int g, int ns) -> size_t {
    size_t cp = (size_t)ns * 8388608;
    size_t ov = prepB > cp ? prepB : cp;
    long KA = (long)g * 2048 + 768;
    size_t ab = pad((size_t)1024 * KA * 2) + pad((size_t)2048 * KA * 2);
    return ov + persB + ab + (2ull << 20);   // 2MiB slack
  };
  // prefer gs=12 (one final GEMM) + nsplit=8 (grid (8,4,8)=256 blocks = 1/CU)
  const int cgs[14] = {12, 12, 12, 6, 6, 4, 3, 2, 2, 1, 1, 1, 1, 1};
  const int cns[14] = { 8,  4, 2, 8, 4, 4, 4, 4, 2, 8, 4, 2, 2, 1};
  int gs = 0, nsplit = 0;
  for (int ci = 0; ci < 14; ci++) {
    if (needB(cgs[ci], cns[ci]) <= ws_size) { gs = cgs[ci]; nsplit = cns[ci]; break; }
  }
  if (gs == 0) { gs = 1; nsplit = 1; }

  const long KA = (long)gs * 2048 + 768;     // A_g/B_g leading dim (K incl. tail)

  char* p = (char*)d_ws;
  auto alloc = [&](size_t bytes) -> char* {
    char* r = p; p += (bytes + 255) & ~(size_t)255; return r;
  };
  // -- overlay region: prep buffers, later reused as Cpart --
  char* overlayBase = p;
  bf16*  WOb    = (bf16*)alloc(12ull * 128 * 768 * 2);
  bf16*  WVt    = (bf16*)alloc(12ull * 128 * 768 * 2);
  bf16*  updWt  = (bf16*)alloc(2048ull * 768 * 2);
  bf16*  Xb     = (bf16*)alloc(1024ull * 768 * 2);
  bf16*  encWb  = (bf16*)alloc(2048ull * 768 * 2);
  bf16*  W_Ot   = (bf16*)alloc(12ull * 768 * 64 * 2);
  bf16*  T1     = (bf16*)alloc(12ull * 1024 * 128 * 2);
  bf16*  T3     = (bf16*)alloc(4ull * 768 * 3072 * 2);
  {
    size_t used = (size_t)(p - overlayBase);
    size_t cp = (size_t)nsplit * 8388608;
    p = overlayBase + (used > cp ? used : cp);
  }
  float* Cpart  = (float*)overlayBase;       // aliases dead prep buffers
  // -- persistent region --
  bf16*  G_t    = (bf16*)alloc(12ull * 2048 * 128 * 2);
  bf16*  Ut     = (bf16*)alloc(4ull * 2048 * 256 * 2);
  bf16*  E1     = (bf16*)alloc(12ull * 2048 * 128 * 2);
  bf16*  probsT = (bf16*)alloc(4ull * 256 * 3072 * 2);
  bf16*  maskb  = (bf16*)alloc(2048ull * 2048 * 2);
  float* invln  = (float*)alloc(1024 * 4);
  float* t_hk   = (float*)alloc(768 * 4);
  float* wv     = (float*)alloc(768 * 4);
  float* c0     = (float*)alloc(2048 * 4);
  float* c1     = (float*)alloc(2048 * 4);
  bf16*  A_g    = (bf16*)alloc((size_t)1024 * KA * 2);
  bf16*  B_g    = (bf16*)alloc((size_t)2048 * KA * 2);

  // ---- prep ----
  k_invln<<<4, 256, 0, stream>>>(lns, invln);
  k_cast4<<<1536, 256, 0, stream>>>(enc_W, encWb, 393216);
  k_probsT<<<3072, 256, 0, stream>>>(probs, probsT);
  k_maskb<<<4096, 256, 0, stream>>>(cmask, maskb, 1048576);
  k_WO<<<4608, 256, 0, stream>>>(W_O, WOb);
  k_WVtT<<<dim3(4, 24, 12), 256, 0, stream>>>(W_V, WVt);
  k_WOt<<<dim3(2, 24, 12), 256, 0, stream>>>(W_O, W_Ot);
  k_updWtT<<<dim3(64, 24), 256, 0, stream>>>(updW, updWt);
  k_Xb<<<768, 256, 0, stream>>>(resid, invln, Xb);
  k_UtT<<<dim3(64, 8, 4), 256, 0, stream>>>(pruned, invln, Ut);
  k_bias_t<<<768, 256, 0, stream>>>(W_V, up_b, t_hk);
  k_bias_w<<<768, 256, 0, stream>>>(W_O, t_hk, wv);
  k_bias_c<<<2048, 256, 0, stream>>>(enc_W, enc_b, b_dec, wv, c0, c1);

  // Merged E1 + G_t (z = 24, bb selects the problem via pointer-diff strides):
  //   bb=0: E1[h][f][k]  = encWb[f,o] . WOb[h][k][o]
  //   bb=1: G_t[h][u][k] = updWt[u,i] . WVt[h][k][i]
  gemm_bt<<<dim3(1, 16, 24), 256, 0, stream>>>(
      encWb, WOb, E1, 2048, 128, 768,
      768, 768, 128, 12,
      (long)(updWt - encWb), 0,
      (long)(WVt - WOb), (long)128 * 768,
      (long)(G_t - E1), (long)2048 * 128,
      0, 0, nullptr, 0);

  // ---- init path: T1 -> T3 -> S (appended into A_g K-tail) ----
  // T1[h][bs][k128] = Xb[bs,i] . WVt[h][k][i]   M=1024 N=128 K=768 (z=h)
  gemm_bt<<<dim3(1, 8, 12), 256, 0, stream>>>(
      Xb, WVt, T1, 1024, 128, 768,
      768, 768, 128, 12,
      0, 0, 0, (long)128 * 768, 0, (long)1024 * 128,
      0, 0, nullptr, 0);

  // T3[b][o][h*256+s] = W_Ot[h][o][k] . T1[h][b*256+s][k]   M=768 N=256 K=64
  // z=(b,h) via batchH=12
  gemm_bt<<<dim3(2, 6, 48), 256, 0, stream>>>(
      W_Ot, T1, T3, 768, 256, 64,
      64, 128, 3072, 12,
      0, (long)768 * 64, (long)256 * 128, (long)1024 * 128, 2359296, 256,
      0, 0, nullptr, 0);

  // S[b][q][o] = probsT[b][q][hs] . T3[b][o][hs]  -> A_g[:, gs*2048 .. +768]
  // M=256 N=768 K=3072 (z=b)
  gemm_bt<<<dim3(6, 2, 4), 256, 0, stream>>>(
      probsT, T3, A_g + (long)gs * 2048, 256, 768, 3072,
      3072, 3072, KA, 1,
      786432, 0, 2359296, 0, 256 * KA, 0,
      0, 0, nullptr, 0);

  // B_g K-tail: enc_W columns (so S @ enc_W^T rides inside the final GEMM)
  k_append<<<768, 256, 0, stream>>>(encWb, B_g + (long)gs * 2048, KA);

  // ---- head-group loop (single iteration when gs==12) ----
  for (int g = 0; g < 12 / gs; g++) {
    // V_g: B_g[f][hh*2048+u] = maskb[f,u] * (E1_h[f,k] . G_t_h[u,k])  K=128
    gemm_bt<<<dim3(16, 16, gs), 256, 0, stream>>>(
        E1 + (long)g * gs * 2048 * 128, G_t + (long)g * gs * 2048 * 128, B_g,
        2048, 2048, 128,
        128, 128, KA, gs,
        0, (long)2048 * 128, 0, (long)2048 * 128, 0, 2048,
        1, 0, maskb, 2048);

    // PU_g: A_g[b*256+q][hh*2048+u] = probsT[b][q][(g*gs+hh)*256 + s] . Ut[b][u][s]
    // M=256 N=2048 K=256, z=(b,hh) via batchH=gs
    gemm_bt<<<dim3(16, 2, 4 * gs), 256, 0, stream>>>(
        probsT + (long)g * gs * 256, Ut, A_g,
        256, 2048, 256,
        3072, 256, KA, gs,
        786432, 256, (long)2048 * 256, 0, 256 * KA, 2048,
        0, 0, nullptr, 0);

    // Cpart (+)= A_g[bq,k] . B_g[f,k]  -- 256x256-tile, phase-split schedule
    // g==0 includes the 768-col [S | enc_W] tail; g>0 only the gs*2048 cols.
    int Kthis = (g == 0) ? (int)KA : gs * 2048;
    int kc = ((Kthis / nsplit + 63) / 64) * 64;
    gemm_fp2<<<dim3(8, 4, nsplit), 512, 0, stream>>>(
        A_g, B_g, Cpart,
        1024, 2048, Kthis,
        KA, KA, 2048,
        (g == 0) ? 2 : 3, kc);
  }

  // out[b,q,f] = fp32( sum_z Cpart + c0[f] + c1[f]*invln[bq] )
  k_out<<<2048, 256, 0, stream>>>(Cpart, c0, c1, invln, out, nsplit);
}

// Round 7
// 450.584 us; speedup vs baseline: 1.1049x; 1.1049x over previous
//
#include <hip/hip_runtime.h>
#include <hip/hip_bf16.h>
#include <stdint.h>

typedef __bf16 bf16;
typedef __bf16 bf16x8 __attribute__((ext_vector_type(8)));
typedef __bf16 bf16x4 __attribute__((ext_vector_type(4)));
typedef float f32x4 __attribute__((ext_vector_type(4)));

#define AS1 __attribute__((address_space(1)))
#define AS3 __attribute__((address_space(3)))

// B=4, S=256, H=12, DH=64(pad 128), D=768, FD=2048, FU=2048
// R26 (this round):
//  - REVERT R25 phase-split (regressed 106.8->112.5us: extra barriers lockstep
//    the waves harder). gemm_fp2 back to R24 form (counted vmcnt, 2 barriers).
//  - V_g K 128->64: E1/G_t are zero for k>=64 (DH padding) -> halve its work.
//  - S-GEMM (P.T3, K=3072) was 48 blocks / ~45us drain-bound. New gemm_bt
//    mode 4 = batched split-K (z = bb*nkc + kc) -> grid (6,2,16)=192 blocks,
//    12 K-steps each, fp32 partials Sp; k_sred reduces+casts into A_g tail.

__device__ __forceinline__ void gld16(const bf16* g, bf16* l) {
  __builtin_amdgcn_global_load_lds((AS1 void*)g, (AS3 void*)l, 16, 0, 0);
}

__global__ void k_sentinel(float* __restrict__ out) {
  int i = blockIdx.x * 256 + threadIdx.x;
  if (i < 2097152) out[i] = 1048576.0f;
}

// ---------------- prep kernels ----------------

__global__ void k_invln(const float* __restrict__ ln, float* __restrict__ invln) {
  int i = blockIdx.x * 256 + threadIdx.x;
  if (i < 1024) invln[i] = 1.0f / ln[i];
}

// vectorized fp32 -> bf16 cast, n4 = n/4
__global__ void k_cast4(const float* __restrict__ s, bf16* __restrict__ d, int n4) {
  int i = blockIdx.x * 256 + threadIdx.x;
  if (i < n4) {
    float4 v = *(const float4*)(s + (long)i * 4);
    bf16x4 o;
    o[0] = (bf16)v.x; o[1] = (bf16)v.y; o[2] = (bf16)v.z; o[3] = (bf16)v.w;
    *(bf16x4*)(d + (long)i * 4) = o;
  }
}

// int32 0/1 mask -> bf16, n4 = n/4
__global__ void k_maskb(const int* __restrict__ m, bf16* __restrict__ d, int n4) {
  int i = blockIdx.x * 256 + threadIdx.x;
  if (i < n4) {
    int4 v = *(const int4*)(m + (long)i * 4);
    bf16x4 o;
    o[0] = (bf16)(float)v.x; o[1] = (bf16)(float)v.y;
    o[2] = (bf16)(float)v.z; o[3] = (bf16)(float)v.w;
    *(bf16x4*)(d + (long)i * 4) = o;
  }
}

// probsT[b][q][h*256+s] = bf16(probs[b,h,q,s])   (contiguous in s both sides)
__global__ void k_probsT(const float* __restrict__ probs, bf16* __restrict__ pT) {
  int i = blockIdx.x * 256 + threadIdx.x;   // 786432 vec4s
  if (i < 786432) {
    long idx = (long)i * 4;
    int s  = (int)(idx & 255);
    int q  = (int)((idx >> 8) & 255);
    int hb = (int)(idx >> 16);
    int h = hb % 12, b = hb / 12;
    float4 v = *(const float4*)(probs + idx);
    bf16x4 o;
    o[0] = (bf16)v.x; o[1] = (bf16)v.y; o[2] = (bf16)v.z; o[3] = (bf16)v.w;
    *(bf16x4*)(pT + (long)b * 786432 + (long)q * 3072 + h * 256 + s) = o;
  }
}

__global__ void k_WO(const float* __restrict__ W_O, bf16* __restrict__ WOb) {
  int i = blockIdx.x * 256 + threadIdx.x;           // 12*128*768
  int o = i % 768, r = (i / 768) & 127, h = i / (768 * 128);
  WOb[i] = (r < 64) ? (bf16)W_O[(long)(h * 64 + r) * 768 + o] : (bf16)0.0f;
}

// WVt[h][k<128][i<768] = W_V[h,i,k]  (tiled transpose, zero-pad k>=64)
__global__ void k_WVtT(const float* __restrict__ wv, bf16* __restrict__ WVt) {
  __shared__ float tile[32][33];
  int h = blockIdx.z;                 // 12
  int k0 = blockIdx.x * 32;           // 0..96
  int i0 = blockIdx.y * 32;           // 24 tiles
  int lane = threadIdx.x & 31, rg = threadIdx.x >> 5;
  if (k0 < 64) {
    for (int r = rg; r < 32; r += 8)
      tile[r][lane] = wv[((long)(h * 768 + i0 + r)) * 64 + k0 + lane];
    __syncthreads();
    for (int r = rg; r < 32; r += 8)
      WVt[((long)h * 128 + k0 + r) * 768 + i0 + lane] = (bf16)tile[lane][r];
  } else {
    for (int r = rg; r < 32; r += 8)
      WVt[((long)h * 128 + k0 + r) * 768 + i0 + lane] = (bf16)0.0f;
  }
}

// W_Ot[h][o][k64] = W_O[h,k,o]  (tiled transpose)
__global__ void k_WOt(const float* __restrict__ wo, bf16* __restrict__ W_Ot) {
  __shared__ float tile[32][33];
  int h = blockIdx.z;                 // 12
  int k0 = blockIdx.x * 32;           // 0..32
  int o0 = blockIdx.y * 32;           // 24 tiles
  int lane = threadIdx.x & 31, rg = threadIdx.x >> 5;
  for (int r = rg; r < 32; r += 8)
    tile[r][lane] = wo[((long)(h * 64 + k0 + r)) * 768 + o0 + lane];
  __syncthreads();
  for (int r = rg; r < 32; r += 8)
    W_Ot[((long)(h * 768 + o0 + r)) * 64 + k0 + lane] = (bf16)tile[lane][r];
}

// updWt[u][i] = up_dec_W[i][u]  (tiled transpose)
__global__ void k_updWtT(const float* __restrict__ u, bf16* __restrict__ d) {
  __shared__ float tile[32][33];
  int u0 = blockIdx.x * 32;           // 64 tiles
  int i0 = blockIdx.y * 32;           // 24 tiles
  int lane = threadIdx.x & 31, rg = threadIdx.x >> 5;
  for (int r = rg; r < 32; r += 8)
    tile[r][lane] = u[((long)(i0 + r)) * 2048 + u0 + lane];
  __syncthreads();
  for (int r = rg; r < 32; r += 8)
    d[((long)(u0 + r)) * 768 + i0 + lane] = (bf16)tile[lane][r];
}

// Xb[b*256+s][d] = resid[b,s,d] * invln (row-major bf16, no transpose)
__global__ void k_Xb(const float* __restrict__ resid, const float* __restrict__ invln,
                     bf16* __restrict__ Xb) {
  int i = blockIdx.x * 256 + threadIdx.x;   // 196608 vec4s
  if (i < 196608) {
    long idx = (long)i * 4;
    float il = invln[idx / 768];            // 4|768 so chunk never straddles rows
    float4 v = *(const float4*)(resid + idx);
    bf16x4 o;
    o[0] = (bf16)(v.x * il); o[1] = (bf16)(v.y * il);
    o[2] = (bf16)(v.z * il); o[3] = (bf16)(v.w * il);
    *(bf16x4*)(Xb + idx) = o;
  }
}

// Ut[b][u][s] = pruned[b,s,u] * invln  (tiled transpose)
__global__ void k_UtT(const float* __restrict__ pr, const float* __restrict__ invln,
                      bf16* __restrict__ Ut) {
  __shared__ float tile[32][33];
  int b = blockIdx.z, u0 = blockIdx.x * 32, s0 = blockIdx.y * 32;  // (64, 8, 4)
  int lane = threadIdx.x & 31, rg = threadIdx.x >> 5;
  for (int r = rg; r < 32; r += 8) {
    int s = s0 + r;
    tile[r][lane] = pr[((long)(b * 256 + s)) * 2048 + u0 + lane] * invln[b * 256 + s];
  }
  __syncthreads();
  for (int r = rg; r < 32; r += 8)
    Ut[((long)b * 2048 + u0 + r) * 256 + s0 + lane] = (bf16)tile[lane][r];
}

// append enc_W (bf16) as the 768-column K-tail of B_g
__global__ void k_append(const bf16* __restrict__ encWb, bf16* __restrict__ Bt, long ldb) {
  int i = blockIdx.x * 256 + threadIdx.x;   // 196608 vec8s
  if (i < 196608) {
    long idx = (long)i * 8;
    int f = (int)(idx / 768), d = (int)(idx % 768);
    *(bf16x8*)(Bt + (long)f * ldb + d) = *(const bf16x8*)(encWb + idx);
  }
}

// reduce 4 fp32 split-K slabs of S and cast into the bf16 A_g K-tail
__global__ void k_sred(const float* __restrict__ Sp, bf16* __restrict__ dst, long ldd) {
  int i = blockIdx.x * 256 + threadIdx.x;   // 196608 vec4s (1024*768/4)
  if (i < 196608) {
    long idx = (long)i * 4;
    int m = (int)(idx / 768), o = (int)(idx % 768);
    float4 v = *(const float4*)(Sp + idx);
    float4 a = *(const float4*)(Sp + 786432 + idx);
    float4 b = *(const float4*)(Sp + 2 * 786432 + idx);
    float4 c = *(const float4*)(Sp + 3 * 786432 + idx);
    v.x += a.x + b.x + c.x; v.y += a.y + b.y + c.y;
    v.z += a.z + b.z + c.z; v.w += a.w + b.w + c.w;
    bf16x4 ov;
    ov[0] = (bf16)v.x; ov[1] = (bf16)v.y; ov[2] = (bf16)v.z; ov[3] = (bf16)v.w;
    *(bf16x4*)(dst + (long)m * ldd + o) = ov;
  }
}

// ---------------- bias chain (fp32, block-parallel) ----------------

__device__ __forceinline__ float blk_reduce(float s) {
  __shared__ float red[256];
  red[threadIdx.x] = s; __syncthreads();
  for (int o = 128; o > 0; o >>= 1) {
    if ((int)threadIdx.x < o) red[threadIdx.x] += red[threadIdx.x + o];
    __syncthreads();
  }
  float r = red[0]; __syncthreads();
  return r;
}

__global__ void k_bias_t(const float* __restrict__ W_V, const float* __restrict__ up_b,
                         float* __restrict__ t_hk) {
  int j = blockIdx.x, h = j >> 6, k = j & 63;
  float s = 0.f;
  for (int m = threadIdx.x; m < 768; m += 256)
    s += W_V[((long)(h * 768 + m)) * 64 + k] * up_b[m];
  float r = blk_reduce(s);
  if (threadIdx.x == 0) t_hk[j] = r;
}

__global__ void k_bias_w(const float* __restrict__ W_O, const float* __restrict__ t_hk,
                         float* __restrict__ w) {
  int d = blockIdx.x;
  float s = 0.f;
  for (int j = threadIdx.x; j < 768; j += 256)
    s += W_O[(long)j * 768 + d] * t_hk[j];
  float r = blk_reduce(s);
  if (threadIdx.x == 0) w[d] = r;
}

__global__ void k_bias_c(const float* __restrict__ enc_W, const float* __restrict__ enc_b,
                         const float* __restrict__ b_dec, const float* __restrict__ w,
                         float* __restrict__ c0, float* __restrict__ c1) {
  int f = blockIdx.x;
  float s0 = 0.f, s1 = 0.f;
  for (int d = threadIdx.x; d < 768; d += 256) {
    float e = enc_W[(long)f * 768 + d];
    s0 += e * b_dec[d];
    s1 += e * w[d];
  }
  float r0 = blk_reduce(s0);
  float r1 = blk_reduce(s1);
  if (threadIdx.x == 0) { c0[f] = enc_b[f] - r0; c1[f] = r1; }
}

// ---------------- GEMM (BT form: C[m,n] = sum_k A[m,k]*B[n,k]) ----------------
// BK=64, XOR-swizzled staging. K (and kChunk) must be multiples of 64.
// mode 0: bf16 store; mode 1: *= bf16 mask, bf16 store;
// mode 2: split-K fp32 overwrite; mode 3: split-K fp32 read-accumulate;
// mode 4: batched split-K fp32 overwrite (z = bb*batchH + kc, batchH = #kc)
__global__ __launch_bounds__(256)
void gemm_bt(const bf16* __restrict__ A, const bf16* __restrict__ B, void* __restrict__ Cv,
             int M, int N, int K,
             long lda, long ldb, long ldc,
             int batchH,
             long sa_b, long sa_h, long sb_b, long sb_h, long sc_b, long sc_h,
             int mode, int kChunk,
             const bf16* __restrict__ mask, long mask_ld)
{
  __shared__ __align__(16) bf16 Asm[128 * 64];
  __shared__ __align__(16) bf16 Bsm[128 * 64];

  const int t = threadIdx.x;

  // bijective XCD-aware remap of the (x,y) tile id (m204 formula)
  const int nbx = gridDim.x, nby = gridDim.y;
  const int nxy = nbx * nby;
  int orig = blockIdx.x + nbx * blockIdx.y;
  int qq = nxy >> 3, rr = nxy & 7;
  int xcd = orig & 7, lid = orig >> 3;
  int swz = (xcd < rr) ? (xcd * (qq + 1) + lid)
                       : (rr * (qq + 1) + (xcd - rr) * qq + lid);
  const int m0 = (swz % nby) * 128;
  const int n0 = (swz / nby) * 128;

  long aoff, boff, coff;
  int k0, k1;
  if (mode == 4) {
    int z = blockIdx.z;
    int bb = z / batchH, kc = z - bb * batchH;
    aoff = (long)bb * sa_b;
    boff = (long)bb * sb_b;
    coff = (long)bb * sc_b + (long)kc * sc_h;
    k0 = kc * kChunk; k1 = k0 + kChunk; if (k1 > K) k1 = K;
  } else if (mode >= 2) {
    int z = blockIdx.z;
    aoff = 0; boff = 0;
    coff = (long)z * (long)M * ldc;
    k0 = z * kChunk; k1 = k0 + kChunk; if (k1 > K) k1 = K;
  } else {
    int z = blockIdx.z;
    int bb = z / batchH, hh = z - bb * batchH;
    aoff = (long)bb * sa_b + (long)hh * sa_h;
    boff = (long)bb * sb_b + (long)hh * sb_h;
    coff = (long)bb * sc_b + (long)hh * sc_h;
    k0 = 0; k1 = K;
  }

  const bf16* Ab = A + aoff + (long)m0 * lda;
  const bf16* Bb = B + boff + (long)n0 * ldb;

  const int r0 = t >> 3;           // 0..31 (staging row within 32-row group)
  const int g8 = t & 7;            // staging col-group (LDS slot)

  const int L = t & 63, w = t >> 6;
  const int wm = (w & 1) * 64, wn = (w >> 1) * 64;
  const int r16 = L & 15, q = L >> 4;

  f32x4 acc[4][4];
#pragma unroll
  for (int i = 0; i < 4; i++)
#pragma unroll
    for (int j = 0; j < 4; j++) acc[i][j] = (f32x4){0.f, 0.f, 0.f, 0.f};

  for (int kt = k0; kt < k1; kt += 64) {
#pragma unroll
    for (int j = 0; j < 4; j++) {
      int row = j * 32 + r0;
      int sc = ((g8 ^ (row & 7)) << 3);      // source col swizzle
      gld16(Ab + (long)row * lda + (kt + sc), &Asm[j * 2048 + t * 8]);
      gld16(Bb + (long)row * ldb + (kt + sc), &Bsm[j * 2048 + t * 8]);
    }
    __syncthreads();

#pragma unroll
    for (int h2 = 0; h2 < 2; h2++) {
      bf16x8 af[4], bfr[4];
#pragma unroll
      for (int i = 0; i < 4; i++) {
        int ra = wm + i * 16 + r16;
        af[i]  = *(const bf16x8*)&Asm[ra * 64 + ((((h2 << 2) + q) ^ (ra & 7)) << 3)];
        int rb = wn + i * 16 + r16;
        bfr[i] = *(const bf16x8*)&Bsm[rb * 64 + ((((h2 << 2) + q) ^ (rb & 7)) << 3)];
      }
#pragma unroll
      for (int mi = 0; mi < 4; mi++)
#pragma unroll
        for (int ni = 0; ni < 4; ni++)
          acc[mi][ni] = __builtin_amdgcn_mfma_f32_16x16x32_bf16(af[mi], bfr[ni], acc[mi][ni], 0, 0, 0);
    }
    __syncthreads();
  }

  if (mode >= 2) {
    float* C = (float*)Cv;
#pragma unroll
    for (int mi = 0; mi < 4; mi++)
#pragma unroll
      for (int ni = 0; ni < 4; ni++)
#pragma unroll
        for (int r = 0; r < 4; r++) {
          int gm = m0 + wm + mi * 16 + q * 4 + r;
          int gn = n0 + wn + ni * 16 + r16;
          long idx = coff + (long)gm * ldc + gn;
          float v = acc[mi][ni][r];
          if (mode == 3) v += C[idx];
          C[idx] = v;
        }
  } else {
    bf16* C = (bf16*)Cv;
#pragma unroll
    for (int mi = 0; mi < 4; mi++)
#pragma unroll
      for (int ni = 0; ni < 4; ni++)
#pragma unroll
        for (int r = 0; r < 4; r++) {
          int gm = m0 + wm + mi * 16 + q * 4 + r;
          int gn = n0 + wn + ni * 16 + r16;
          float v = acc[mi][ni][r];
          if (mode == 1) v *= (float)mask[(long)gm * mask_ld + gn];
          C[coff + (long)gm * ldc + gn] = (bf16)v;
        }
  }
}

// ------------- 256x256-tile split-K GEMM (final GEMM only) -------------------
// C[m,n] (+)= sum_k A[m,k]*B[n,k], fp32 C. 512 threads = 8 waves (2M x 4N),
// per-wave 128x64 output. BK=64. 2 LDS buffers (128 KiB), depth-1 prefetch,
// counted vmcnt(8) (0 only at epilogue), 2 barriers per K-step.  [R24 form]
// Work remap: z_slab = flat_id % nz (flat_id%8 = XCD) -> each XCD owns one
// K-slab; hot window ~384KB << 4MiB L2 (R24: FETCH 253->76MB).
// K, kChunk multiples of 64. mode 2 = overwrite, 3 = read-accumulate.
__global__ __launch_bounds__(512, 2)
void gemm_fp2(const bf16* __restrict__ A, const bf16* __restrict__ B,
              float* __restrict__ C,
              int M, int N, int K, long lda, long ldb, long ldc,
              int mode, int kChunk)
{
  __shared__ __align__(16) bf16 SM[2][2][16384];   // [buf][A|B][256*64]

  const int t = threadIdx.x;

  const int nz = gridDim.z;
  int fid = blockIdx.x + gridDim.x * (blockIdx.y + gridDim.y * blockIdx.z);
  const int z  = fid % nz;                 // K-slab, constant per XCD when nz=8
  const int t2 = fid / nz;                 // 0..31 (m,n)-tile within the slab
  const int m0 = (t2 >> 3) * 256;          // 4 m-tiles
  const int n0 = (t2 & 7) * 256;           // 8 n-tiles

  const long coff = (long)z * (long)M * ldc;
  int k0 = z * kChunk, k1 = k0 + kChunk; if (k1 > K) k1 = K;
  const int NT = (k1 > k0) ? (k1 - k0) >> 6 : 0;

  const bf16* Ab = A + (long)m0 * lda + k0;
  const bf16* Bb = B + (long)n0 * ldb + k0;

  const int sr = t >> 3;           // 0..63 staging row within 64-row group
  const int g8 = t & 7;            // staging col-group (LDS slot)

  const int L = t & 63, w = t >> 6;          // 8 waves
  const int wm = (w & 1) * 128;              // 2 waves over M (256)
  const int wn = (w >> 1) * 64;              // 4 waves over N (256)
  const int r16 = L & 15, q = L >> 4;

  f32x4 acc[8][4];
#pragma unroll
  for (int i = 0; i < 8; i++)
#pragma unroll
    for (int j = 0; j < 4; j++) acc[i][j] = (f32x4){0.f, 0.f, 0.f, 0.f};

  // stage K-tile tt into buffer buf: 8 gld16 per thread (4 A rounds, 4 B)
  auto stage = [&](int tt, int buf) {
    const bf16* Ap = Ab + (long)tt * 64;
    const bf16* Bp = Bb + (long)tt * 64;
#pragma unroll
    for (int j = 0; j < 4; j++) {
      int row = j * 64 + sr;
      int sc = ((g8 ^ (row & 7)) << 3);
      gld16(Ap + (long)row * lda + sc, &SM[buf][0][j * 4096 + t * 8]);
    }
#pragma unroll
    for (int j = 0; j < 4; j++) {
      int row = j * 64 + sr;
      int sc = ((g8 ^ (row & 7)) << 3);
      gld16(Bp + (long)row * ldb + sc, &SM[buf][1][j * 4096 + t * 8]);
    }
  };

  if (NT >= 1) stage(0, 0);

  for (int tt = 0; tt < NT; tt++) {
    if (tt + 1 < NT) {
      stage(tt + 1, (tt + 1) & 1);           // prefetch next into other buffer
      asm volatile("s_waitcnt vmcnt(8)" ::: "memory");   // stage(tt) done
    } else {
      asm volatile("s_waitcnt vmcnt(0)" ::: "memory");   // epilogue drain
    }
    __builtin_amdgcn_s_barrier();            // buffer tt&1 ready for all waves

    const bf16* As = &SM[tt & 1][0][0];
    const bf16* Bs = &SM[tt & 1][1][0];
#pragma unroll
    for (int h2 = 0; h2 < 2; h2++) {
      bf16x8 af[8], bfr[4];
#pragma unroll
      for (int i = 0; i < 8; i++) {
        int ra = wm + i * 16 + r16;
        af[i]  = *(const bf16x8*)&As[ra * 64 + ((((h2 << 2) + q) ^ (ra & 7)) << 3)];
      }
#pragma unroll
      for (int i = 0; i < 4; i++) {
        int rb = wn + i * 16 + r16;
        bfr[i] = *(const bf16x8*)&Bs[rb * 64 + ((((h2 << 2) + q) ^ (rb & 7)) << 3)];
      }
#pragma unroll
      for (int mi = 0; mi < 8; mi++)
#pragma unroll
        for (int ni = 0; ni < 4; ni++)
          acc[mi][ni] = __builtin_amdgcn_mfma_f32_16x16x32_bf16(af[mi], bfr[ni], acc[mi][ni], 0, 0, 0);
    }
    __builtin_amdgcn_s_barrier();            // all waves done reading buf tt&1
  }

#pragma unroll
  for (int mi = 0; mi < 8; mi++)
#pragma unroll
    for (int ni = 0; ni < 4; ni++)
#pragma unroll
      for (int r = 0; r < 4; r++) {
        int gm = m0 + wm + mi * 16 + q * 4 + r;
        int gn = n0 + wn + ni * 16 + r16;
        long idx = coff + (long)gm * ldc + gn;
        float v = acc[mi][ni][r];
        if (mode == 3) v += C[idx];
        C[idx] = v;
      }
}

// ---------------- final reduce + bias epilogue (fp32 out, float4) ------------
__global__ void k_out(const float* __restrict__ Cp, const float* __restrict__ c0,
                      const float* __restrict__ c1, const float* __restrict__ invln,
                      float* __restrict__ out, int nsplit) {
  int i4 = blockIdx.x * 256 + threadIdx.x;          // 524288
  long i = (long)i4 * 4;
  int n = (int)(i & 2047), m = (int)(i >> 11);
  float4 v = *(const float4*)(Cp + i);
  for (int z = 1; z < nsplit; z++) {
    float4 u = *(const float4*)(Cp + i + (long)z * 2097152);
    v.x += u.x; v.y += u.y; v.z += u.z; v.w += u.w;
  }
  float il = invln[m];
  float4 a = *(const float4*)(c0 + n);
  float4 b = *(const float4*)(c1 + n);
  v.x += a.x + b.x * il;
  v.y += a.y + b.y * il;
  v.z += a.z + b.z * il;
  v.w += a.w + b.w * il;
  *(float4*)(out + i) = v;
}

// ---------------- host ----------------

extern "C" void kernel_launch(void* const* d_in, const int* in_sizes, int n_in,
                              void* d_out, int out_size, void* d_ws, size_t ws_size,
                              hipStream_t stream) {
  (void)out_size;
  float* out = (float*)d_out;

  // ---- resolve inputs by size (order-agnostic) ----
  int iresid = -1, iln = -1, iprobs = -1, iencb = -1, ipruned = -1, imask = -1;
  int iwo = -1, iwv = -1, iencw = -1, iupdw = -1, ibdec = -1, iupb = -1;
  for (int i = 0; i < n_in; i++) {
    switch (in_sizes[i]) {
      case 786432:  iresid  = i; break;
      case 1024:    iln     = i; break;
      case 3145728: iprobs  = i; break;
      case 2048:    iencb   = i; break;
      case 2097152: ipruned = i; break;
      case 4194304: imask   = i; break;
      case 589824:  if (iwo   < 0) iwo   = i; else iwv   = i; break;
      case 1572864: if (iencw < 0) iencw = i; else iupdw = i; break;
      case 768:     if (ibdec < 0) ibdec = i; else iupb  = i; break;
      default: break;
    }
  }
  bool ok = n_in == 12 && iresid >= 0 && iln >= 0 && iprobs >= 0 && iencb >= 0 &&
            ipruned >= 0 && imask >= 0 && iwo >= 0 && iwv >= 0 && iencw >= 0 &&
            iupdw >= 0 && ibdec >= 0 && iupb >= 0;
  if (!ok) { k_sentinel<<<8192, 256, 0, stream>>>(out); return; }

  const float* resid = (const float*)d_in[iresid];
  const float* lns   = (const float*)d_in[iln];
  const float* probs = (const float*)d_in[iprobs];
  const float* W_O   = (const float*)d_in[iwo];
  const float* W_V   = (const float*)d_in[iwv];
  const float* enc_W = (const float*)d_in[iencw];
  const float* enc_b = (const float*)d_in[iencb];
  const float* b_dec = (const float*)d_in[ibdec];
  const float* updW  = (const float*)d_in[iupdw];
  const float* up_b  = (const float*)d_in[iupb];
  const float* pruned= (const float*)d_in[ipruned];
  const int*   cmask = (const int*)d_in[imask];

  // ---- workspace sizing ----
  auto pad = [](size_t b) -> size_t { return (b + 255) & ~(size_t)255; };
  // overlay prep buffers (ALL dead before the first final-GEMM dispatch),
  // now including Sp (S split-K fp32 partials, 4 x 1024 x 768 x 4B):
  const size_t prepB = pad(2359296) + pad(2359296) + pad(3145728) + pad(1572864) +
                       pad(3145728) + pad(1179648) + pad(3145728) + pad(18874368) +
                       pad(12582912);
  // persistent (live across the g-loop): G_t, Ut, E1, probsT, maskb + smalls
  const size_t persB = pad(6291456) + pad(4194304) + pad(6291456) + pad(6291456) +
                       pad(8388608) + pad(4096) + pad(3072) + pad(3072) +
                       pad(8192) + pad(8192);
  auto needB = [&](int g, int ns) -> size_t {
    size_t cp = (size_t)ns * 8388608;
    size_t ov = prepB > cp ? prepB : cp;
    long KA = (long)g * 2048 + 768;
    size_t ab = pad((size_t)1024 * KA * 2) + pad((size_t)2048 * KA * 2);
    return ov + persB + ab + (2ull << 20);   // 2MiB slack
  };
  // prefer gs=12 (one final GEMM) + nsplit=8 (grid (8,4,8)=256 blocks = 1/CU)
  const int cgs[14] = {12, 12, 12, 6, 6, 4, 3, 2, 2, 1, 1, 1, 1, 1};
  const int cns[14] = { 8,  4, 2, 8, 4, 4, 4, 4, 2, 8, 4, 2, 2, 1};
  int gs = 0, nsplit = 0;
  for (int ci = 0; ci < 14; ci++) {
    if (needB(cgs[ci], cns[ci]) <= ws_size) { gs = cgs[ci]; nsplit = cns[ci]; break; }
  }
  if (gs == 0) { gs = 1; nsplit = 1; }

  const long KA = (long)gs * 2048 + 768;     // A_g/B_g leading dim (K incl. tail)

  char* p = (char*)d_ws;
  auto alloc = [&](size_t bytes) -> char* {
    char* r = p; p += (bytes + 255) & ~(size_t)255; return r;
  };
  // -- overlay region: prep buffers, later reused as Cpart --
  char* overlayBase = p;
  bf16*  WOb    = (bf16*)alloc(12ull * 128 * 768 * 2);
  bf16*  WVt    = (bf16*)alloc(12ull * 128 * 768 * 2);
  bf16*  updWt  = (bf16*)alloc(2048ull * 768 * 2);
  bf16*  Xb     = (bf16*)alloc(1024ull * 768 * 2);
  bf16*  encWb  = (bf16*)alloc(2048ull * 768 * 2);
  bf16*  W_Ot   = (bf16*)alloc(12ull * 768 * 64 * 2);
  bf16*  T1     = (bf16*)alloc(12ull * 1024 * 128 * 2);
  bf16*  T3     = (bf16*)alloc(4ull * 768 * 3072 * 2);
  float* Sp     = (float*)alloc(4ull * 1024 * 768 * 4);
  {
    size_t used = (size_t)(p - overlayBase);
    size_t cp = (size_t)nsplit * 8388608;
    p = overlayBase + (used > cp ? used : cp);
  }
  float* Cpart  = (float*)overlayBase;       // aliases dead prep buffers
  // -- persistent region --
  bf16*  G_t    = (bf16*)alloc(12ull * 2048 * 128 * 2);
  bf16*  Ut     = (bf16*)alloc(4ull * 2048 * 256 * 2);
  bf16*  E1     = (bf16*)alloc(12ull * 2048 * 128 * 2);
  bf16*  probsT = (bf16*)alloc(4ull * 256 * 3072 * 2);
  bf16*  maskb  = (bf16*)alloc(2048ull * 2048 * 2);
  float* invln  = (float*)alloc(1024 * 4);
  float* t_hk   = (float*)alloc(768 * 4);
  float* wv     = (float*)alloc(768 * 4);
  float* c0     = (float*)alloc(2048 * 4);
  float* c1     = (float*)alloc(2048 * 4);
  bf16*  A_g    = (bf16*)alloc((size_t)1024 * KA * 2);
  bf16*  B_g    = (bf16*)alloc((size_t)2048 * KA * 2);

  // ---- prep ----
  k_invln<<<4, 256, 0, stream>>>(lns, invln);
  k_cast4<<<1536, 256, 0, stream>>>(enc_W, encWb, 393216);
  k_probsT<<<3072, 256, 0, stream>>>(probs, probsT);
  k_maskb<<<4096, 256, 0, stream>>>(cmask, maskb, 1048576);
  k_WO<<<4608, 256, 0, stream>>>(W_O, WOb);
  k_WVtT<<<dim3(4, 24, 12), 256, 0, stream>>>(W_V, WVt);
  k_WOt<<<dim3(2, 24, 12), 256, 0, stream>>>(W_O, W_Ot);
  k_updWtT<<<dim3(64, 24), 256, 0, stream>>>(updW, updWt);
  k_Xb<<<768, 256, 0, stream>>>(resid, invln, Xb);
  k_UtT<<<dim3(64, 8, 4), 256, 0, stream>>>(pruned, invln, Ut);
  k_bias_t<<<768, 256, 0, stream>>>(W_V, up_b, t_hk);
  k_bias_w<<<768, 256, 0, stream>>>(W_O, t_hk, wv);
  k_bias_c<<<2048, 256, 0, stream>>>(enc_W, enc_b, b_dec, wv, c0, c1);

  // Merged E1 + G_t (z = 24, bb selects the problem via pointer-diff strides):
  //   bb=0: E1[h][f][k]  = encWb[f,o] . WOb[h][k][o]
  //   bb=1: G_t[h][u][k] = updWt[u,i] . WVt[h][k][i]
  gemm_bt<<<dim3(1, 16, 24), 256, 0, stream>>>(
      encWb, WOb, E1, 2048, 128, 768,
      768, 768, 128, 12,
      (long)(updWt - encWb), 0,
      (long)(WVt - WOb), (long)128 * 768,
      (long)(G_t - E1), (long)2048 * 128,
      0, 0, nullptr, 0);

  // ---- init path: T1 -> T3 -> S (split-K) -> reduce into A_g K-tail ----
  // T1[h][bs][k128] = Xb[bs,i] . WVt[h][k][i]   M=1024 N=128 K=768 (z=h)
  gemm_bt<<<dim3(1, 8, 12), 256, 0, stream>>>(
      Xb, WVt, T1, 1024, 128, 768,
      768, 768, 128, 12,
      0, 0, 0, (long)128 * 768, 0, (long)1024 * 128,
      0, 0, nullptr, 0);

  // T3[b][o][h*256+s] = W_Ot[h][o][k] . T1[h][b*256+s][k]   M=768 N=256 K=64
  // z=(b,h) via batchH=12
  gemm_bt<<<dim3(2, 6, 48), 256, 0, stream>>>(
      W_Ot, T1, T3, 768, 256, 64,
      64, 128, 3072, 12,
      0, (long)768 * 64, (long)256 * 128, (long)1024 * 128, 2359296, 256,
      0, 0, nullptr, 0);

  // S (mode 4, batched split-K): Sp[kc][b][q][o] = probsT[b][q][kc-chunk of hs]
  //   . T3[b][o][same chunk].  M=256 N=768 K=3072, z = bb*4 + kc (16 z-blocks,
  //   192 blocks total vs 48 before), kChunk=768 -> 12 K-steps per block.
  gemm_bt<<<dim3(6, 2, 16), 256, 0, stream>>>(
      probsT, T3, Sp, 256, 768, 3072,
      3072, 3072, 768, 4,
      786432, 0, 2359296, 0, 196608, 786432,
      4, 768, nullptr, 0);

  // reduce 4 Sp slabs + cast -> A_g[:, gs*2048 .. +768]
  k_sred<<<768, 256, 0, stream>>>(Sp, A_g + (long)gs * 2048, KA);

  // B_g K-tail: enc_W columns (so S @ enc_W^T rides inside the final GEMM)
  k_append<<<768, 256, 0, stream>>>(encWb, B_g + (long)gs * 2048, KA);

  // ---- head-group loop (single iteration when gs==12) ----
  for (int g = 0; g < 12 / gs; g++) {
    // V_g: B_g[f][hh*2048+u] = maskb[f,u] * (E1_h[f,k] . G_t_h[u,k])
    // K=64 (not 128): E1/G_t are zero for k>=64 (DH padding) -> half the work.
    gemm_bt<<<dim3(16, 16, gs), 256, 0, stream>>>(
        E1 + (long)g * gs * 2048 * 128, G_t + (long)g * gs * 2048 * 128, B_g,
        2048, 2048, 64,
        128, 128, KA, gs,
        0, (long)2048 * 128, 0, (long)2048 * 128, 0, 2048,
        1, 0, maskb, 2048);

    // PU_g: A_g[b*256+q][hh*2048+u] = probsT[b][q][(g*gs+hh)*256 + s] . Ut[b][u][s]
    // M=256 N=2048 K=256, z=(b,hh) via batchH=gs
    gemm_bt<<<dim3(16, 2, 4 * gs), 256, 0, stream>>>(
        probsT + (long)g * gs * 256, Ut, A_g,
        256, 2048, 256,
        3072, 256, KA, gs,
        786432, 256, (long)2048 * 256, 0, 256 * KA, 2048,
        0, 0, nullptr, 0);

    // Cpart (+)= A_g[bq,k] . B_g[f,k]  -- 256x256-tile, z-per-XCD locality
    // g==0 includes the 768-col [S | enc_W] tail; g>0 only the gs*2048 cols.
    int Kthis = (g == 0) ? (int)KA : gs * 2048;
    int kc = ((Kthis / nsplit + 63) / 64) * 64;
    gemm_fp2<<<dim3(8, 4, nsplit), 512, 0, stream>>>(
        A_g, B_g, Cpart,
        1024, 2048, Kthis,
        KA, KA, 2048,
        (g == 0) ? 2 : 3, kc);
  }

  // out[b,q,f] = fp32( sum_z Cpart + c0[f] + c1[f]*invln[bq] )
  k_out<<<2048, 256, 0, stream>>>(Cpart, c0, c1, invln, out, nsplit);
}

// Round 8
// 444.458 us; speedup vs baseline: 1.1201x; 1.0138x over previous
//
#include <hip/hip_runtime.h>
#include <hip/hip_bf16.h>
#include <stdint.h>

typedef __bf16 bf16;
typedef __bf16 bf16x8 __attribute__((ext_vector_type(8)));
typedef __bf16 bf16x4 __attribute__((ext_vector_type(4)));
typedef float f32x4 __attribute__((ext_vector_type(4)));

#define AS1 __attribute__((address_space(1)))
#define AS3 __attribute__((address_space(3)))

// B=4, S=256, H=12, DH=64(pad 128), D=768, FD=2048, FU=2048
// R27 (this round):
//  - Final GEMM: per-block MFMA=51us, LDS-read=48us, measured 105 = SUM (one
//    block/CU -> pipes serialize; barriers can't fix it, R25 proved). New
//    gemm_fp3: BM=128 BN=256 BK=32, LDS 48KiB, acc[4][4] (<=128 VGPR),
//    grid (8,8,8)=512 blocks = TWO blocks/CU -> cross-block pipe overlap.
//    2-way-free LDS swizzle for 64B rows: slot = q ^ ((row>>1)&3).
//  - Launch-count cut 24->14: k_prep merges 7 elementwise preps (1/ln inline),
//    k_prepT merges the 4 LDS-tiled transposes.

__device__ __forceinline__ void gld16(const bf16* g, bf16* l) {
  __builtin_amdgcn_global_load_lds((AS1 void*)g, (AS3 void*)l, 16, 0, 0);
}

__global__ void k_sentinel(float* __restrict__ out) {
  int i = blockIdx.x * 256 + threadIdx.x;
  if (i < 2097152) out[i] = 1048576.0f;
}

// ---------------- merged elementwise prep ----------------
// sections (256-thr blocks): s0 invln[1], s1 encWb[1536], s2 probsT[3072],
// s3 maskb[4096], s4 WOb[1152], s5 Xb[768], s6 BgTail[1536]  -> 12161 blocks
__global__ void k_prep(const float* __restrict__ lns, float* __restrict__ invln,
                       const float* __restrict__ enc_W, bf16* __restrict__ encWb,
                       const float* __restrict__ probs, bf16* __restrict__ probsT,
                       const int* __restrict__ cmask, bf16* __restrict__ maskb,
                       const float* __restrict__ W_O, bf16* __restrict__ WOb,
                       const float* __restrict__ resid, bf16* __restrict__ Xb,
                       bf16* __restrict__ BgTail, long ldTail) {
  const int bid = blockIdx.x, t = threadIdx.x;
  if (bid < 1) {                                  // s0: invln (1024)
    for (int k = 0; k < 4; k++) { int j = t + k * 256; invln[j] = 1.0f / lns[j]; }
  } else if (bid < 1537) {                        // s1: encWb cast (393216 v4)
    long idx = ((long)(bid - 1) * 256 + t) * 4;
    float4 v = *(const float4*)(enc_W + idx);
    bf16x4 o; o[0]=(bf16)v.x; o[1]=(bf16)v.y; o[2]=(bf16)v.z; o[3]=(bf16)v.w;
    *(bf16x4*)(encWb + idx) = o;
  } else if (bid < 4609) {                        // s2: probsT (786432 v4)
    long idx = ((long)(bid - 1537) * 256 + t) * 4;
    int s = (int)(idx & 255), q = (int)((idx >> 8) & 255);
    int hb = (int)(idx >> 16), h = hb % 12, b = hb / 12;
    float4 v = *(const float4*)(probs + idx);
    bf16x4 o; o[0]=(bf16)v.x; o[1]=(bf16)v.y; o[2]=(bf16)v.z; o[3]=(bf16)v.w;
    *(bf16x4*)(probsT + (long)b * 786432 + (long)q * 3072 + h * 256 + s) = o;
  } else if (bid < 8705) {                        // s3: maskb (1048576 v4)
    long idx = ((long)(bid - 4609) * 256 + t) * 4;
    int4 v = *(const int4*)(cmask + idx);
    bf16x4 o; o[0]=(bf16)(float)v.x; o[1]=(bf16)(float)v.y;
    o[2]=(bf16)(float)v.z; o[3]=(bf16)(float)v.w;
    *(bf16x4*)(maskb + idx) = o;
  } else if (bid < 9857) {                        // s4: WOb (294912 v4)
    long idx = ((long)(bid - 8705) * 256 + t) * 4;
    int o = (int)(idx % 768), r = (int)((idx / 768) & 127), h = (int)(idx / (768 * 128));
    bf16x4 ov;
    if (r < 64) {
      float4 v = *(const float4*)(W_O + (long)(h * 64 + r) * 768 + o);
      ov[0]=(bf16)v.x; ov[1]=(bf16)v.y; ov[2]=(bf16)v.z; ov[3]=(bf16)v.w;
    } else { ov[0]=ov[1]=ov[2]=ov[3]=(bf16)0.0f; }
    *(bf16x4*)(WOb + idx) = ov;
  } else if (bid < 10625) {                       // s5: Xb (196608 v4)
    long idx = ((long)(bid - 9857) * 256 + t) * 4;
    float il = 1.0f / lns[idx / 768];
    float4 v = *(const float4*)(resid + idx);
    bf16x4 o; o[0]=(bf16)(v.x*il); o[1]=(bf16)(v.y*il);
    o[2]=(bf16)(v.z*il); o[3]=(bf16)(v.w*il);
    *(bf16x4*)(Xb + idx) = o;
  } else {                                        // s6: B_g K-tail (393216 v4)
    long idx = ((long)(bid - 10625) * 256 + t) * 4;
    int f = (int)(idx / 768), d = (int)(idx % 768);
    float4 v = *(const float4*)(enc_W + idx);
    bf16x4 o; o[0]=(bf16)v.x; o[1]=(bf16)v.y; o[2]=(bf16)v.z; o[3]=(bf16)v.w;
    *(bf16x4*)(BgTail + (long)f * ldTail + d) = o;
  }
}

// ---------------- merged tiled transposes ----------------
// zones: WVt[1152] WOt[576] updWt[1536] Ut[2048] -> 5312 blocks
__global__ void k_prepT(const float* __restrict__ wv, bf16* __restrict__ WVt,
                        const float* __restrict__ wo, bf16* __restrict__ W_Ot,
                        const float* __restrict__ updW, bf16* __restrict__ updWt,
                        const float* __restrict__ pr, const float* __restrict__ lns,
                        bf16* __restrict__ Ut) {
  __shared__ float tile[32][33];
  const int bid = blockIdx.x;
  int lane = threadIdx.x & 31, rg = threadIdx.x >> 5;
  if (bid < 1152) {                 // WVt[h][k<128][i<768] = W_V[h,i,k]
    int r0 = bid;
    int x = r0 % 4, y = (r0 / 4) % 24, h = r0 / 96;
    int k0 = x * 32, i0 = y * 32;
    if (k0 < 64) {
      for (int r = rg; r < 32; r += 8)
        tile[r][lane] = wv[((long)(h * 768 + i0 + r)) * 64 + k0 + lane];
      __syncthreads();
      for (int r = rg; r < 32; r += 8)
        WVt[((long)h * 128 + k0 + r) * 768 + i0 + lane] = (bf16)tile[lane][r];
    } else {
      for (int r = rg; r < 32; r += 8)
        WVt[((long)h * 128 + k0 + r) * 768 + i0 + lane] = (bf16)0.0f;
    }
  } else if (bid < 1728) {          // W_Ot[h][o][k64] = W_O[h,k,o]
    int r0 = bid - 1152;
    int x = r0 % 2, y = (r0 / 2) % 24, h = r0 / 48;
    int k0 = x * 32, o0 = y * 32;
    for (int r = rg; r < 32; r += 8)
      tile[r][lane] = wo[((long)(h * 64 + k0 + r)) * 768 + o0 + lane];
    __syncthreads();
    for (int r = rg; r < 32; r += 8)
      W_Ot[((long)(h * 768 + o0 + r)) * 64 + k0 + lane] = (bf16)tile[lane][r];
  } else if (bid < 3264) {          // updWt[u][i] = up_dec_W[i][u]
    int r0 = bid - 1728;
    int u0 = (r0 % 64) * 32, i0 = (r0 / 64) * 32;
    for (int r = rg; r < 32; r += 8)
      tile[r][lane] = updW[((long)(i0 + r)) * 2048 + u0 + lane];
    __syncthreads();
    for (int r = rg; r < 32; r += 8)
      updWt[((long)(u0 + r)) * 768 + i0 + lane] = (bf16)tile[lane][r];
  } else {                          // Ut[b][u][s] = pruned[b,s,u]/ln
    int r0 = bid - 3264;
    int u0 = (r0 % 64) * 32, s0 = ((r0 / 64) % 8) * 32, b = r0 / 512;
    for (int r = rg; r < 32; r += 8) {
      int s = s0 + r;
      tile[r][lane] = pr[((long)(b * 256 + s)) * 2048 + u0 + lane] *
                      (1.0f / lns[b * 256 + s]);
    }
    __syncthreads();
    for (int r = rg; r < 32; r += 8)
      Ut[((long)b * 2048 + u0 + r) * 256 + s0 + lane] = (bf16)tile[lane][r];
  }
}

// reduce 4 fp32 split-K slabs of S and cast into the bf16 A_g K-tail
__global__ void k_sred(const float* __restrict__ Sp, bf16* __restrict__ dst, long ldd) {
  int i = blockIdx.x * 256 + threadIdx.x;   // 196608 vec4s
  if (i < 196608) {
    long idx = (long)i * 4;
    int m = (int)(idx / 768), o = (int)(idx % 768);
    float4 v = *(const float4*)(Sp + idx);
    float4 a = *(const float4*)(Sp + 786432 + idx);
    float4 b = *(const float4*)(Sp + 2 * 786432 + idx);
    float4 c = *(const float4*)(Sp + 3 * 786432 + idx);
    v.x += a.x + b.x + c.x; v.y += a.y + b.y + c.y;
    v.z += a.z + b.z + c.z; v.w += a.w + b.w + c.w;
    bf16x4 ov;
    ov[0] = (bf16)v.x; ov[1] = (bf16)v.y; ov[2] = (bf16)v.z; ov[3] = (bf16)v.w;
    *(bf16x4*)(dst + (long)m * ldd + o) = ov;
  }
}

// ---------------- bias chain (fp32, block-parallel) ----------------

__device__ __forceinline__ float blk_reduce(float s) {
  __shared__ float red[256];
  red[threadIdx.x] = s; __syncthreads();
  for (int o = 128; o > 0; o >>= 1) {
    if ((int)threadIdx.x < o) red[threadIdx.x] += red[threadIdx.x + o];
    __syncthreads();
  }
  float r = red[0]; __syncthreads();
  return r;
}

__global__ void k_bias_t(const float* __restrict__ W_V, const float* __restrict__ up_b,
                         float* __restrict__ t_hk) {
  int j = blockIdx.x, h = j >> 6, k = j & 63;
  float s = 0.f;
  for (int m = threadIdx.x; m < 768; m += 256)
    s += W_V[((long)(h * 768 + m)) * 64 + k] * up_b[m];
  float r = blk_reduce(s);
  if (threadIdx.x == 0) t_hk[j] = r;
}

__global__ void k_bias_w(const float* __restrict__ W_O, const float* __restrict__ t_hk,
                         float* __restrict__ w) {
  int d = blockIdx.x;
  float s = 0.f;
  for (int j = threadIdx.x; j < 768; j += 256)
    s += W_O[(long)j * 768 + d] * t_hk[j];
  float r = blk_reduce(s);
  if (threadIdx.x == 0) w[d] = r;
}

__global__ void k_bias_c(const float* __restrict__ enc_W, const float* __restrict__ enc_b,
                         const float* __restrict__ b_dec, const float* __restrict__ w,
                         float* __restrict__ c0, float* __restrict__ c1) {
  int f = blockIdx.x;
  float s0 = 0.f, s1 = 0.f;
  for (int d = threadIdx.x; d < 768; d += 256) {
    float e = enc_W[(long)f * 768 + d];
    s0 += e * b_dec[d];
    s1 += e * w[d];
  }
  float r0 = blk_reduce(s0);
  float r1 = blk_reduce(s1);
  if (threadIdx.x == 0) { c0[f] = enc_b[f] - r0; c1[f] = r1; }
}

// ---------------- GEMM (BT form: C[m,n] = sum_k A[m,k]*B[n,k]) ----------------
// BK=64, XOR-swizzled staging. K (and kChunk) must be multiples of 64.
// mode 0: bf16 store; mode 1: *= bf16 mask, bf16 store;
// mode 2: split-K fp32 overwrite; mode 3: split-K fp32 read-accumulate;
// mode 4: batched split-K fp32 overwrite (z = bb*batchH + kc, batchH = #kc)
__global__ __launch_bounds__(256)
void gemm_bt(const bf16* __restrict__ A, const bf16* __restrict__ B, void* __restrict__ Cv,
             int M, int N, int K,
             long lda, long ldb, long ldc,
             int batchH,
             long sa_b, long sa_h, long sb_b, long sb_h, long sc_b, long sc_h,
             int mode, int kChunk,
             const bf16* __restrict__ mask, long mask_ld)
{
  __shared__ __align__(16) bf16 Asm[128 * 64];
  __shared__ __align__(16) bf16 Bsm[128 * 64];

  const int t = threadIdx.x;

  // bijective XCD-aware remap of the (x,y) tile id (m204 formula)
  const int nbx = gridDim.x, nby = gridDim.y;
  const int nxy = nbx * nby;
  int orig = blockIdx.x + nbx * blockIdx.y;
  int qq = nxy >> 3, rr = nxy & 7;
  int xcd = orig & 7, lid = orig >> 3;
  int swz = (xcd < rr) ? (xcd * (qq + 1) + lid)
                       : (rr * (qq + 1) + (xcd - rr) * qq + lid);
  const int m0 = (swz % nby) * 128;
  const int n0 = (swz / nby) * 128;

  long aoff, boff, coff;
  int k0, k1;
  if (mode == 4) {
    int z = blockIdx.z;
    int bb = z / batchH, kc = z - bb * batchH;
    aoff = (long)bb * sa_b;
    boff = (long)bb * sb_b;
    coff = (long)bb * sc_b + (long)kc * sc_h;
    k0 = kc * kChunk; k1 = k0 + kChunk; if (k1 > K) k1 = K;
  } else if (mode >= 2) {
    int z = blockIdx.z;
    aoff = 0; boff = 0;
    coff = (long)z * (long)M * ldc;
    k0 = z * kChunk; k1 = k0 + kChunk; if (k1 > K) k1 = K;
  } else {
    int z = blockIdx.z;
    int bb = z / batchH, hh = z - bb * batchH;
    aoff = (long)bb * sa_b + (long)hh * sa_h;
    boff = (long)bb * sb_b + (long)hh * sb_h;
    coff = (long)bb * sc_b + (long)hh * sc_h;
    k0 = 0; k1 = K;
  }

  const bf16* Ab = A + aoff + (long)m0 * lda;
  const bf16* Bb = B + boff + (long)n0 * ldb;

  const int r0 = t >> 3;           // 0..31 (staging row within 32-row group)
  const int g8 = t & 7;            // staging col-group (LDS slot)

  const int L = t & 63, w = t >> 6;
  const int wm = (w & 1) * 64, wn = (w >> 1) * 64;
  const int r16 = L & 15, q = L >> 4;

  f32x4 acc[4][4];
#pragma unroll
  for (int i = 0; i < 4; i++)
#pragma unroll
    for (int j = 0; j < 4; j++) acc[i][j] = (f32x4){0.f, 0.f, 0.f, 0.f};

  for (int kt = k0; kt < k1; kt += 64) {
#pragma unroll
    for (int j = 0; j < 4; j++) {
      int row = j * 32 + r0;
      int sc = ((g8 ^ (row & 7)) << 3);      // source col swizzle
      gld16(Ab + (long)row * lda + (kt + sc), &Asm[j * 2048 + t * 8]);
      gld16(Bb + (long)row * ldb + (kt + sc), &Bsm[j * 2048 + t * 8]);
    }
    __syncthreads();

#pragma unroll
    for (int h2 = 0; h2 < 2; h2++) {
      bf16x8 af[4], bfr[4];
#pragma unroll
      for (int i = 0; i < 4; i++) {
        int ra = wm + i * 16 + r16;
        af[i]  = *(const bf16x8*)&Asm[ra * 64 + ((((h2 << 2) + q) ^ (ra & 7)) << 3)];
        int rb = wn + i * 16 + r16;
        bfr[i] = *(const bf16x8*)&Bsm[rb * 64 + ((((h2 << 2) + q) ^ (rb & 7)) << 3)];
      }
#pragma unroll
      for (int mi = 0; mi < 4; mi++)
#pragma unroll
        for (int ni = 0; ni < 4; ni++)
          acc[mi][ni] = __builtin_amdgcn_mfma_f32_16x16x32_bf16(af[mi], bfr[ni], acc[mi][ni], 0, 0, 0);
    }
    __syncthreads();
  }

  if (mode >= 2) {
    float* C = (float*)Cv;
#pragma unroll
    for (int mi = 0; mi < 4; mi++)
#pragma unroll
      for (int ni = 0; ni < 4; ni++)
#pragma unroll
        for (int r = 0; r < 4; r++) {
          int gm = m0 + wm + mi * 16 + q * 4 + r;
          int gn = n0 + wn + ni * 16 + r16;
          long idx = coff + (long)gm * ldc + gn;
          float v = acc[mi][ni][r];
          if (mode == 3) v += C[idx];
          C[idx] = v;
        }
  } else {
    bf16* C = (bf16*)Cv;
#pragma unroll
    for (int mi = 0; mi < 4; mi++)
#pragma unroll
      for (int ni = 0; ni < 4; ni++)
#pragma unroll
        for (int r = 0; r < 4; r++) {
          int gm = m0 + wm + mi * 16 + q * 4 + r;
          int gn = n0 + wn + ni * 16 + r16;
          float v = acc[mi][ni][r];
          if (mode == 1) v *= (float)mask[(long)gm * mask_ld + gn];
          C[coff + (long)gm * ldc + gn] = (bf16)v;
        }
  }
}

// ------------- 128x256-tile split-K GEMM, 2 blocks/CU (final GEMM) -----------
// C[m,n] (+)= sum_k A[m,k]*B[n,k], fp32 C. 512 threads = 8 waves (2M x 4N),
// per-wave 64x64 output, acc[4][4] (64 VGPR -> <=128 total -> 4 waves/SIMD).
// BK=32. LDS 48 KiB (2 bufs x [A 8K | B 16K]) -> TWO blocks/CU: the two
// independent blocks cross-fill the LDS-read and MFMA pipes that serialize
// with one block (R26 math: 51us MFMA + 48us LDS executed as SUM).
// 2-way-free bank swizzle for 64B rows: slot = q ^ ((row>>1)&3), same XOR on
// the staging source column (involution).
// Work remap: z = fid % nz -> z-slab per XCD (R24: FETCH 253->76MB).
// K, kChunk multiples of 64. mode 2 = overwrite, 3 = read-accumulate.
__global__ __launch_bounds__(512, 4)
void gemm_fp3(const bf16* __restrict__ A, const bf16* __restrict__ B,
              float* __restrict__ C,
              int M, int N, int K, long lda, long ldb, long ldc,
              int mode, int kChunk)
{
  __shared__ __align__(16) bf16 SM[2][12288];   // [buf][A 4096 | B 8192] elems

  const int t = threadIdx.x;

  const int nz = gridDim.z;
  int fid = blockIdx.x + gridDim.x * (blockIdx.y + gridDim.y * blockIdx.z);
  const int z  = fid % nz;                 // K-slab, constant per XCD when nz=8
  const int t2 = fid / nz;                 // 0..63 (m,n)-tile within the slab
  const int m0 = (t2 & 7) * 128;           // 8 m-tiles
  const int n0 = (t2 >> 3) * 256;          // 8 n-tiles

  const long coff = (long)z * (long)M * ldc;
  int k0 = z * kChunk, k1 = k0 + kChunk; if (k1 > K) k1 = K;
  const int NT = (k1 > k0) ? (k1 - k0) >> 5 : 0;   // BK=32

  const bf16* Ab = A + (long)m0 * lda + k0;
  const bf16* Bb = B + (long)n0 * ldb + k0;

  const int L = t & 63, w = t >> 6;          // 8 waves
  const int wm = (w & 1) * 64;               // 2 waves over M (128)
  const int wn = (w >> 1) * 64;              // 4 waves over N (256)
  const int r16 = L & 15, q = L >> 4;

  f32x4 acc[4][4];
#pragma unroll
  for (int i = 0; i < 4; i++)
#pragma unroll
    for (int j = 0; j < 4; j++) acc[i][j] = (f32x4){0.f, 0.f, 0.f, 0.f};

  // stage K-tile tt (32 cols): A 1 gld16/thread, B 2 gld16/thread.
  // slot layout: [row][g2] (4 x 16B groups per 64B row), source col-group
  // pre-swizzled by g2 ^ ((row>>1)&3).
  auto stage = [&](int tt, int buf) {
    const bf16* Ap = Ab + (long)tt * 32;
    const bf16* Bp = Bb + (long)tt * 32;
    {
      int row = t >> 2, g2 = t & 3;
      gld16(Ap + (long)row * lda + ((g2 ^ ((row >> 1) & 3)) << 3), &SM[buf][t * 8]);
    }
#pragma unroll
    for (int j = 0; j < 2; j++) {
      int slot = j * 512 + t;
      int row = slot >> 2, g2 = slot & 3;
      gld16(Bp + (long)row * ldb + ((g2 ^ ((row >> 1) & 3)) << 3),
            &SM[buf][4096 + slot * 8]);
    }
  };

  if (NT >= 1) stage(0, 0);

  for (int tt = 0; tt < NT; tt++) {
    if (tt + 1 < NT) {
      stage(tt + 1, (tt + 1) & 1);           // prefetch next into other buffer
      asm volatile("s_waitcnt vmcnt(3)" ::: "memory");   // stage(tt) done
    } else {
      asm volatile("s_waitcnt vmcnt(0)" ::: "memory");   // epilogue drain
    }
    __builtin_amdgcn_s_barrier();            // buffer tt&1 ready for all waves

    const bf16* As = &SM[tt & 1][0];
    const bf16* Bs = &SM[tt & 1][4096];
    bf16x8 af[4], bfr[4];
#pragma unroll
    for (int i = 0; i < 4; i++) {
      int ra = wm + i * 16 + r16;
      af[i]  = *(const bf16x8*)&As[ra * 32 + ((q ^ ((ra >> 1) & 3)) << 3)];
    }
#pragma unroll
    for (int i = 0; i < 4; i++) {
      int rb = wn + i * 16 + r16;
      bfr[i] = *(const bf16x8*)&Bs[rb * 32 + ((q ^ ((rb >> 1) & 3)) << 3)];
    }
#pragma unroll
    for (int mi = 0; mi < 4; mi++)
#pragma unroll
      for (int ni = 0; ni < 4; ni++)
        acc[mi][ni] = __builtin_amdgcn_mfma_f32_16x16x32_bf16(af[mi], bfr[ni], acc[mi][ni], 0, 0, 0);
    __builtin_amdgcn_s_barrier();            // all waves done reading buf tt&1
  }

#pragma unroll
  for (int mi = 0; mi < 4; mi++)
#pragma unroll
    for (int ni = 0; ni < 4; ni++)
#pragma unroll
      for (int r = 0; r < 4; r++) {
        int gm = m0 + wm + mi * 16 + q * 4 + r;
        int gn = n0 + wn + ni * 16 + r16;
        long idx = coff + (long)gm * ldc + gn;
        float v = acc[mi][ni][r];
        if (mode == 3) v += C[idx];
        C[idx] = v;
      }
}

// ---------------- final reduce + bias epilogue (fp32 out, float4) ------------
__global__ void k_out(const float* __restrict__ Cp, const float* __restrict__ c0,
                      const float* __restrict__ c1, const float* __restrict__ invln,
                      float* __restrict__ out, int nsplit) {
  int i4 = blockIdx.x * 256 + threadIdx.x;          // 524288
  long i = (long)i4 * 4;
  int n = (int)(i & 2047), m = (int)(i >> 11);
  float4 v = *(const float4*)(Cp + i);
  for (int z = 1; z < nsplit; z++) {
    float4 u = *(const float4*)(Cp + i + (long)z * 2097152);
    v.x += u.x; v.y += u.y; v.z += u.z; v.w += u.w;
  }
  float il = invln[m];
  float4 a = *(const float4*)(c0 + n);
  float4 b = *(const float4*)(c1 + n);
  v.x += a.x + b.x * il;
  v.y += a.y + b.y * il;
  v.z += a.z + b.z * il;
  v.w += a.w + b.w * il;
  *(float4*)(out + i) = v;
}

// ---------------- host ----------------

extern "C" void kernel_launch(void* const* d_in, const int* in_sizes, int n_in,
                              void* d_out, int out_size, void* d_ws, size_t ws_size,
                              hipStream_t stream) {
  (void)out_size;
  float* out = (float*)d_out;

  // ---- resolve inputs by size (order-agnostic) ----
  int iresid = -1, iln = -1, iprobs = -1, iencb = -1, ipruned = -1, imask = -1;
  int iwo = -1, iwv = -1, iencw = -1, iupdw = -1, ibdec = -1, iupb = -1;
  for (int i = 0; i < n_in; i++) {
    switch (in_sizes[i]) {
      case 786432:  iresid  = i; break;
      case 1024:    iln     = i; break;
      case 3145728: iprobs  = i; break;
      case 2048:    iencb   = i; break;
      case 2097152: ipruned = i; break;
      case 4194304: imask   = i; break;
      case 589824:  if (iwo   < 0) iwo   = i; else iwv   = i; break;
      case 1572864: if (iencw < 0) iencw = i; else iupdw = i; break;
      case 768:     if (ibdec < 0) ibdec = i; else iupb  = i; break;
      default: break;
    }
  }
  bool ok = n_in == 12 && iresid >= 0 && iln >= 0 && iprobs >= 0 && iencb >= 0 &&
            ipruned >= 0 && imask >= 0 && iwo >= 0 && iwv >= 0 && iencw >= 0 &&
            iupdw >= 0 && ibdec >= 0 && iupb >= 0;
  if (!ok) { k_sentinel<<<8192, 256, 0, stream>>>(out); return; }

  const float* resid = (const float*)d_in[iresid];
  const float* lns   = (const float*)d_in[iln];
  const float* probs = (const float*)d_in[iprobs];
  const float* W_O   = (const float*)d_in[iwo];
  const float* W_V   = (const float*)d_in[iwv];
  const float* enc_W = (const float*)d_in[iencw];
  const float* enc_b = (const float*)d_in[iencb];
  const float* b_dec = (const float*)d_in[ibdec];
  const float* updW  = (const float*)d_in[iupdw];
  const float* up_b  = (const float*)d_in[iupb];
  const float* pruned= (const float*)d_in[ipruned];
  const int*   cmask = (const int*)d_in[imask];

  // ---- workspace sizing ----
  auto pad = [](size_t b) -> size_t { return (b + 255) & ~(size_t)255; };
  const size_t prepB = pad(2359296) + pad(2359296) + pad(3145728) + pad(1572864) +
                       pad(3145728) + pad(1179648) + pad(3145728) + pad(18874368) +
                       pad(12582912);
  const size_t persB = pad(6291456) + pad(4194304) + pad(6291456) + pad(6291456) +
                       pad(8388608) + pad(4096) + pad(3072) + pad(3072) +
                       pad(8192) + pad(8192);
  auto needB = [&](int g, int ns) -> size_t {
    size_t cp = (size_t)ns * 8388608;
    size_t ov = prepB > cp ? prepB : cp;
    long KA = (long)g * 2048 + 768;
    size_t ab = pad((size_t)1024 * KA * 2) + pad((size_t)2048 * KA * 2);
    return ov + persB + ab + (2ull << 20);   // 2MiB slack
  };
  const int cgs[14] = {12, 12, 12, 6, 6, 4, 3, 2, 2, 1, 1, 1, 1, 1};
  const int cns[14] = { 8,  4, 2, 8, 4, 4, 4, 4, 2, 8, 4, 2, 2, 1};
  int gs = 0, nsplit = 0;
  for (int ci = 0; ci < 14; ci++) {
    if (needB(cgs[ci], cns[ci]) <= ws_size) { gs = cgs[ci]; nsplit = cns[ci]; break; }
  }
  if (gs == 0) { gs = 1; nsplit = 1; }

  const long KA = (long)gs * 2048 + 768;     // A_g/B_g leading dim (K incl. tail)

  char* p = (char*)d_ws;
  auto alloc = [&](size_t bytes) -> char* {
    char* r = p; p += (bytes + 255) & ~(size_t)255; return r;
  };
  // -- overlay region: prep buffers, later reused as Cpart --
  char* overlayBase = p;
  bf16*  WOb    = (bf16*)alloc(12ull * 128 * 768 * 2);
  bf16*  WVt    = (bf16*)alloc(12ull * 128 * 768 * 2);
  bf16*  updWt  = (bf16*)alloc(2048ull * 768 * 2);
  bf16*  Xb     = (bf16*)alloc(1024ull * 768 * 2);
  bf16*  encWb  = (bf16*)alloc(2048ull * 768 * 2);
  bf16*  W_Ot   = (bf16*)alloc(12ull * 768 * 64 * 2);
  bf16*  T1     = (bf16*)alloc(12ull * 1024 * 128 * 2);
  bf16*  T3     = (bf16*)alloc(4ull * 768 * 3072 * 2);
  float* Sp     = (float*)alloc(4ull * 1024 * 768 * 4);
  {
    size_t used = (size_t)(p - overlayBase);
    size_t cp = (size_t)nsplit * 8388608;
    p = overlayBase + (used > cp ? used : cp);
  }
  float* Cpart  = (float*)overlayBase;       // aliases dead prep buffers
  // -- persistent region --
  bf16*  G_t    = (bf16*)alloc(12ull * 2048 * 128 * 2);
  bf16*  Ut     = (bf16*)alloc(4ull * 2048 * 256 * 2);
  bf16*  E1     = (bf16*)alloc(12ull * 2048 * 128 * 2);
  bf16*  probsT = (bf16*)alloc(4ull * 256 * 3072 * 2);
  bf16*  maskb  = (bf16*)alloc(2048ull * 2048 * 2);
  float* invln  = (float*)alloc(1024 * 4);
  float* t_hk   = (float*)alloc(768 * 4);
  float* wv     = (float*)alloc(768 * 4);
  float* c0     = (float*)alloc(2048 * 4);
  float* c1     = (float*)alloc(2048 * 4);
  bf16*  A_g    = (bf16*)alloc((size_t)1024 * KA * 2);
  bf16*  B_g    = (bf16*)alloc((size_t)2048 * KA * 2);

  // ---- prep (2 merged kernels + bias chain) ----
  k_prep<<<12161, 256, 0, stream>>>(lns, invln, enc_W, encWb, probs, probsT,
                                    cmask, maskb, W_O, WOb, resid, Xb,
                                    B_g + (long)gs * 2048, KA);
  k_prepT<<<5312, 256, 0, stream>>>(W_V, WVt, W_O, W_Ot, updW, updWt,
                                    pruned, lns, Ut);
  k_bias_t<<<768, 256, 0, stream>>>(W_V, up_b, t_hk);
  k_bias_w<<<768, 256, 0, stream>>>(W_O, t_hk, wv);
  k_bias_c<<<2048, 256, 0, stream>>>(enc_W, enc_b, b_dec, wv, c0, c1);

  // Merged E1 + G_t (z = 24, bb selects the problem via pointer-diff strides):
  //   bb=0: E1[h][f][k]  = encWb[f,o] . WOb[h][k][o]
  //   bb=1: G_t[h][u][k] = updWt[u,i] . WVt[h][k][i]
  gemm_bt<<<dim3(1, 16, 24), 256, 0, stream>>>(
      encWb, WOb, E1, 2048, 128, 768,
      768, 768, 128, 12,
      (long)(updWt - encWb), 0,
      (long)(WVt - WOb), (long)128 * 768,
      (long)(G_t - E1), (long)2048 * 128,
      0, 0, nullptr, 0);

  // ---- init path: T1 -> T3 -> S (split-K) -> reduce into A_g K-tail ----
  // T1[h][bs][k128] = Xb[bs,i] . WVt[h][k][i]   M=1024 N=128 K=768 (z=h)
  gemm_bt<<<dim3(1, 8, 12), 256, 0, stream>>>(
      Xb, WVt, T1, 1024, 128, 768,
      768, 768, 128, 12,
      0, 0, 0, (long)128 * 768, 0, (long)1024 * 128,
      0, 0, nullptr, 0);

  // T3[b][o][h*256+s] = W_Ot[h][o][k] . T1[h][b*256+s][k]   M=768 N=256 K=64
  gemm_bt<<<dim3(2, 6, 48), 256, 0, stream>>>(
      W_Ot, T1, T3, 768, 256, 64,
      64, 128, 3072, 12,
      0, (long)768 * 64, (long)256 * 128, (long)1024 * 128, 2359296, 256,
      0, 0, nullptr, 0);

  // S (mode 4, batched split-K): 16 z-blocks, kChunk=768 -> 12 K-steps each.
  gemm_bt<<<dim3(6, 2, 16), 256, 0, stream>>>(
      probsT, T3, Sp, 256, 768, 3072,
      3072, 3072, 768, 4,
      786432, 0, 2359296, 0, 196608, 786432,
      4, 768, nullptr, 0);

  // reduce 4 Sp slabs + cast -> A_g[:, gs*2048 .. +768]
  k_sred<<<768, 256, 0, stream>>>(Sp, A_g + (long)gs * 2048, KA);

  // ---- head-group loop (single iteration when gs==12) ----
  for (int g = 0; g < 12 / gs; g++) {
    // V_g: B_g[f][hh*2048+u] = maskb[f,u] * (E1_h[f,k] . G_t_h[u,k])  K=64
    gemm_bt<<<dim3(16, 16, gs), 256, 0, stream>>>(
        E1 + (long)g * gs * 2048 * 128, G_t + (long)g * gs * 2048 * 128, B_g,
        2048, 2048, 64,
        128, 128, KA, gs,
        0, (long)2048 * 128, 0, (long)2048 * 128, 0, 2048,
        1, 0, maskb, 2048);

    // PU_g: A_g[b*256+q][hh*2048+u] = probsT[b][q][(g*gs+hh)*256 + s] . Ut[b][u][s]
    gemm_bt<<<dim3(16, 2, 4 * gs), 256, 0, stream>>>(
        probsT + (long)g * gs * 256, Ut, A_g,
        256, 2048, 256,
        3072, 256, KA, gs,
        786432, 256, (long)2048 * 256, 0, 256 * KA, 2048,
        0, 0, nullptr, 0);

    // Cpart (+)= A_g[bq,k] . B_g[f,k]  -- 128x256-tile, 2 blocks/CU
    int Kthis = (g == 0) ? (int)KA : gs * 2048;
    int kc = ((Kthis / nsplit + 63) / 64) * 64;
    gemm_fp3<<<dim3(8, 8, nsplit), 512, 0, stream>>>(
        A_g, B_g, Cpart,
        1024, 2048, Kthis,
        KA, KA, 2048,
        (g == 0) ? 2 : 3, kc);
  }

  // out[b,q,f] = fp32( sum_z Cpart + c0[f] + c1[f]*invln[bq] )
  k_out<<<2048, 256, 0, stream>>>(Cpart, c0, c1, invln, out, nsplit);
}